// Round 20
// baseline (394.537 us; speedup 1.0000x reference)
//
#include <hip/hip_runtime.h>

#define DD 128
#define KTOT 384
#define BM 128
#define BS_BITS 10
#define BS 1024          // nodes per bucket
#define NBMAX 512        // max buckets (4N <= 512K)
#define CHUNK 2048       // edges per bin_edges block
#define CAP 12288        // stage slots per bucket (max expected ~10.6K)

typedef __attribute__((ext_vector_type(8))) short short8;
typedef __attribute__((ext_vector_type(8))) unsigned short ushort8;
typedef __attribute__((ext_vector_type(4))) float floatx4;
typedef __attribute__((ext_vector_type(2))) float floatx2;

__device__ __forceinline__ unsigned short f2b(float f) {
    union { float f; unsigned u; } v; v.f = f;
    return (unsigned short)((v.u + 0x7fffu + ((v.u >> 16) & 1u)) >> 16);
}
__device__ __forceinline__ float b2f(unsigned short u) {
    union { unsigned u; float f; } v; v.u = ((unsigned)u) << 16;
    return v.f;
}
__device__ __forceinline__ float asf(unsigned u) {
    union { unsigned u; float f; } v; v.u = u; return v.f;
}

// bf16 pair-accumulate: u32 = (bf16_hi<<16)|bf16_lo (R16-verified)
#define ACC_PAIR(accL, accH, u) { accH += asf(u); accL += asf((u) << 16); }

// decode 8 fp8 (e4m3) from uint2 and accumulate into acc[8] — HW packed cvt
#define ACC_F8(acc, ux, uy) { \
    floatx2 p0 = __builtin_amdgcn_cvt_pk_f32_fp8((ux), false); \
    floatx2 p1 = __builtin_amdgcn_cvt_pk_f32_fp8((ux), true);  \
    floatx2 p2 = __builtin_amdgcn_cvt_pk_f32_fp8((uy), false); \
    floatx2 p3 = __builtin_amdgcn_cvt_pk_f32_fp8((uy), true);  \
    acc[0] += p0.x; acc[1] += p0.y; acc[2] += p1.x; acc[3] += p1.y; \
    acc[4] += p2.x; acc[5] += p2.y; acc[6] += p3.x; acc[7] += p3.y; }

// ---------------- edge dtype probe: int64 arrays have all-zero odd int32 words ----------
__global__ __launch_bounds__(256) void detect_i32(const int* __restrict__ p, int nodd,
                                                  int* __restrict__ flag)
{
    int i = blockIdx.x * 256 + threadIdx.x;
    if (i < nodd && p[2 * i + 1] != 0) atomicOr(flag, 1);
}

// ---------------- x -> bf16 (row-major) + fp8 gather mirror ----------------
__global__ __launch_bounds__(256) void cvt_bf16(const float* __restrict__ in,
                                                unsigned short* __restrict__ out,
                                                unsigned char* __restrict__ out8, int n8)
{
    int i = blockIdx.x * 256 + threadIdx.x;
    if (i >= n8) return;
    float4 v0 = *(const float4*)(in + (size_t)i * 8);
    float4 v1 = *(const float4*)(in + (size_t)i * 8 + 4);
    ushort8 r;
    r[0]=f2b(v0.x); r[1]=f2b(v0.y); r[2]=f2b(v0.z); r[3]=f2b(v0.w);
    r[4]=f2b(v1.x); r[5]=f2b(v1.y); r[6]=f2b(v1.z); r[7]=f2b(v1.w);
    *(ushort8*)(out + (size_t)i * 8) = r;
    unsigned a = 0, b = 0;
    a = __builtin_amdgcn_cvt_pk_fp8_f32(v0.x, v0.y, a, false);
    a = __builtin_amdgcn_cvt_pk_fp8_f32(v0.z, v0.w, a, true);
    b = __builtin_amdgcn_cvt_pk_fp8_f32(v1.x, v1.y, b, false);
    b = __builtin_amdgcn_cvt_pk_fp8_f32(v1.z, v1.w, b, true);
    *(uint2*)(out8 + (size_t)i * 8) = make_uint2(a, b);
}

// ---------------- weight prep: WT_t = combined W^T in fragment-tiled layout ------------
__global__ __launch_bounds__(256) void build_wcomb(
    const float* __restrict__ Wl, const float* __restrict__ bl,
    const float* __restrict__ Wr, unsigned short* __restrict__ WTt, float* __restrict__ bc)
{
    int idx = blockIdx.x * 256 + threadIdx.x;
    if (idx < 2 * 2 * DD * KTOT) {
        int k  = idx % KTOT;
        int t1 = idx / KTOT;
        int i  = t1 & 127;
        int t2 = t1 >> 7;
        int dt = t2 & 1;      // 0 = dst d, 1 = dst m
        int l  = t2 >> 1;
        int ta = dt ? 1 : 0;  // d: dd(0), m: mm(1)
        int tb = dt ? 2 : 3;  // d: md(3), m: dm(2)
        float v;
        if (k < 128) {
            v = Wl[(((size_t)(l * 4 + ta) * 128 + i) << 7) + k];
        } else if (k < 256) {
            v = Wl[(((size_t)(l * 4 + tb) * 128 + i) << 7) + (k - 128)];
        } else {
            int kk = k - 256;
            v = Wr[(((size_t)(l * 4 + ta) * 128 + i) << 7) + kk]
              + Wr[(((size_t)(l * 4 + tb) * 128 + i) << 7) + kk];
        }
        int tidx = ((((i >> 4) * 12 + (k >> 5)) * 64) + (((k >> 3) & 3) * 16 + (i & 15))) * 8
                 + (k & 7);
        WTt[(size_t)t2 * (DD * KTOT) + tidx] = f2b(v);
    }
    if (idx < 512) {
        int i  = idx & 127;
        int t2 = idx >> 7;
        int dt = t2 & 1;
        int l  = t2 >> 1;
        int ta = dt ? 1 : 0;
        int tb = dt ? 2 : 3;
        bc[idx] = bl[(l * 4 + ta) * 128 + i] + bl[(l * 4 + tb) * 128 + i];
    }
}

// ---------------- phase A: LDS-binned edge staging, fixed-CAP bucket regions ----------
__global__ __launch_bounds__(512) void bin_edges(
    const void* __restrict__ e0, const void* __restrict__ e1,
    const void* __restrict__ e2, const void* __restrict__ e3,
    int E0, int E1, int E2, int E3,
    const int* __restrict__ flag, int* __restrict__ bucket_fill,
    unsigned* __restrict__ stage,
    unsigned long long* __restrict__ ovf, int* __restrict__ ovf_cnt,
    int N, int nb)
{
    __shared__ unsigned sb_pack[CHUNK];
    __shared__ unsigned short sb_b[CHUNK];
    __shared__ int hist[NBMAX];
    __shared__ int offs[NBMAX];
    __shared__ int base[NBMAX];

    const int tid   = threadIdx.x;
    const int E_tot = E0 + E1 + E2 + E3;
    const int e_bas = blockIdx.x * CHUNK;
    const int e_end = min(e_bas + CHUNK, E_tot);
    const int cnt_e = e_end - e_bas;
    const int isI32 = *flag;

    for (int i = tid; i < nb; i += 512) hist[i] = 0;
    __syncthreads();

    unsigned my_pack[4];
    int my_b[4], my_r[4];
    #pragma unroll
    for (int u = 0; u < 4; ++u) {
        my_b[u] = -1;
        int e = e_bas + tid + u * 512;
        if (e < e_end) {
            const void* ep; int El, type, le = e;
            if (le < E0)              { ep = e0; El = E0; type = 0; }
            else if ((le -= E0) < E1) { ep = e1; El = E1; type = 1; }
            else if ((le -= E1) < E2) { ep = e2; El = E2; type = 2; }
            else                      { le -= E2; ep = e3; El = E3; type = 3; }
            int s, d;
            if (isI32) {
                s = ((const int*)ep)[le];
                d = ((const int*)ep)[(size_t)El + le];
            } else {
                s = (int)((const long long*)ep)[le];
                d = (int)((const long long*)ep)[(size_t)El + le];
            }
            int gnode = type * N + d;
            int b = gnode >> BS_BITS;
            my_b[u]    = b;
            my_pack[u] = ((unsigned)s << BS_BITS) | (unsigned)(gnode & (BS - 1));
            my_r[u]    = atomicAdd(&hist[b], 1);
        }
    }
    __syncthreads();

    offs[tid] = (tid < nb) ? hist[tid] : 0;
    __syncthreads();
    for (int d = 1; d < 512; d <<= 1) {
        int v = (tid >= d) ? offs[tid - d] : 0;
        __syncthreads();
        offs[tid] += v;
        __syncthreads();
    }
    if (tid < nb) {
        offs[tid] -= hist[tid];                              // exclusive
        base[tid] = hist[tid] ? atomicAdd(&bucket_fill[tid], hist[tid]) : 0;
    }
    __syncthreads();

    #pragma unroll
    for (int u = 0; u < 4; ++u) {
        if (my_b[u] >= 0) {
            int pos = offs[my_b[u]] + my_r[u];
            sb_pack[pos] = my_pack[u];
            sb_b[pos]    = (unsigned short)my_b[u];
        }
    }
    __syncthreads();

    for (int pos = tid; pos < cnt_e; pos += 512) {
        int b = sb_b[pos];
        unsigned p = sb_pack[pos];
        int idx = base[b] + (pos - offs[b]);
        if (idx < CAP) {
            stage[(size_t)b * CAP + idx] = p;
        } else {                                             // overflow (expected: never)
            int k = atomicAdd(ovf_cnt, 1);
            int gnode = (b << BS_BITS) | (int)(p & (BS - 1));
            ovf[k] = ((unsigned long long)(unsigned)gnode << 32) | (p >> BS_BITS);
        }
    }
}

// ---------------- exclusive scan over bucket totals (1 block) ----------------
__global__ __launch_bounds__(512) void scan_buckets(const int* __restrict__ fill, int nb,
                                                    int* __restrict__ base)
{
    __shared__ int s[512];
    const int tid = threadIdx.x;
    int v = (tid < nb) ? fill[tid] : 0;
    s[tid] = v;
    __syncthreads();
    for (int d = 1; d < 512; d <<= 1) {
        int u = (tid >= d) ? s[tid - d] : 0;
        __syncthreads();
        s[tid] += u;
        __syncthreads();
    }
    if (tid < nb) base[tid] = s[tid] - v;    // exclusive
}

// ---------------- phase B: per-bucket count + scan + rp/inv + CSR fill ----------------
__global__ __launch_bounds__(512) void fill_from_stage(
    const unsigned* __restrict__ stage, const int* __restrict__ bucket_fill,
    const int* __restrict__ bucket_base,
    const unsigned long long* __restrict__ ovf, const int* __restrict__ ovf_cnt,
    int* __restrict__ rp_all, float* __restrict__ inv_all, int* __restrict__ col, int n4)
{
    __shared__ int cl[BS];     // counts, later cursors
    __shared__ int rl[BS];     // exclusive scan
    __shared__ int w[512];

    const int tid   = threadIdx.x;
    const int b     = blockIdx.x;
    const int node0 = b << BS_BITS;
    const int nn    = min(BS, n4 - node0);

    cl[tid] = 0; cl[tid + 512] = 0;
    __syncthreads();

    const int total  = bucket_fill[b];
    const int nstage = min(total, CAP);
    const unsigned* st = stage + (size_t)b * CAP;
    const int novf = *ovf_cnt;

    for (int j = tid; j < nstage; j += 512)
        atomicAdd(&cl[st[j] & (BS - 1)], 1);
    for (int k = tid; k < novf; k += 512) {
        int g = (int)(ovf[k] >> 32);
        if (g >= node0 && g < node0 + nn) atomicAdd(&cl[g - node0], 1);
    }
    __syncthreads();

    int a0 = cl[2 * tid], a1 = cl[2 * tid + 1];
    w[tid] = a0 + a1;
    __syncthreads();
    for (int d = 1; d < 512; d <<= 1) {
        int v = (tid >= d) ? w[tid - d] : 0;
        __syncthreads();
        w[tid] += v;
        __syncthreads();
    }
    int excl = w[tid] - a0 - a1;
    rl[2 * tid]     = excl;
    rl[2 * tid + 1] = excl + a0;
    __syncthreads();

    const int gbase = bucket_base[b];
    for (int i = tid; i < nn; i += 512) {
        rp_all[node0 + i] = gbase + rl[i];
        inv_all[node0 + i] = 1.0f / (float)max(cl[i], 1);
    }
    if (b == gridDim.x - 1 && tid == 0) rp_all[n4] = gbase + total;
    __syncthreads();

    for (int i = tid; i < BS; i += 512) cl[i] = gbase + rl[i];
    __syncthreads();

    for (int j = tid; j < nstage; j += 512) {
        unsigned p = st[j];
        int slot = atomicAdd(&cl[p & (BS - 1)], 1);
        col[slot] = (int)(p >> BS_BITS);
    }
    for (int k = tid; k < novf; k += 512) {
        unsigned long long p = ovf[k];
        int g = (int)(p >> 32);
        if (g >= node0 && g < node0 + nn) {
            int slot = atomicAdd(&cl[g - node0], 1);
            col[slot] = (int)(p & 0xffffffffu);
        }
    }
}

// ---------------- gather-aggregate BOTH dst types into fragment-tiled A_t ----------------
// MIXED precision: segA (tree, deg~1, no error averaging) gathers bf16 x;
//                  segB (link, deg~10, mean smooths fp8 noise) gathers fp8 x8.
__global__ __launch_bounds__(256) void aggregate_all(
    const unsigned short* __restrict__ x, const unsigned char* __restrict__ x8,
    const int* __restrict__ rp, const float* __restrict__ inv,
    const int* __restrict__ col, unsigned short* __restrict__ At, int N)
{
    long long g = (long long)blockIdx.x * 256 + threadIdx.x;
    int node = (int)(g >> 4);
    int q    = (int)(g & 15);          // lane: 8 elems (16 B bf16 / 8 B fp8)
    if (node >= 2 * N) return;

    const int isM  = node >= N;
    const int segA = node + (isM ? N : 0);
    const int segB = segA + N;
    const int selfbase  = isM ? N : 0;
    const int otherbase = N - selfbase;

    const int r16 = node >> 4;
    const int fr  = node & 15;
    unsigned short* tbase = At + ((size_t)r16 * 8 + (q >> 2)) * 512 + ((q & 3) * 16 + fr) * 8;

    const unsigned short* xs = x  + (size_t)selfbase  * DD + q * 8;   // bf16 self
    const unsigned char*  xo = x8 + (size_t)otherbase * DD + q * 8;   // fp8 other

    float aL[4], aH[4], accB[8];
    #pragma unroll
    for (int t = 0; t < 4; ++t) { aL[t]=0.f; aH[t]=0.f; }
    #pragma unroll
    for (int t = 0; t < 8; ++t) accB[t] = 0.f;

    int jA = rp[segA], eA = rp[segA + 1];
    int jB = rp[segB], eB = rp[segB + 1];

    // ---- segB: fp8, 8-deep independent loads ----
    while (jB + 8 <= eB) {
        int b0 = col[jB],   b1 = col[jB+1], b2 = col[jB+2], b3 = col[jB+3];
        int b4 = col[jB+4], b5 = col[jB+5], b6 = col[jB+6], b7 = col[jB+7];
        uint2 v0 = *(const uint2*)(xo + (size_t)b0 * DD);
        uint2 v1 = *(const uint2*)(xo + (size_t)b1 * DD);
        uint2 v2 = *(const uint2*)(xo + (size_t)b2 * DD);
        uint2 v3 = *(const uint2*)(xo + (size_t)b3 * DD);
        uint2 v4 = *(const uint2*)(xo + (size_t)b4 * DD);
        uint2 v5 = *(const uint2*)(xo + (size_t)b5 * DD);
        uint2 v6 = *(const uint2*)(xo + (size_t)b6 * DD);
        uint2 v7 = *(const uint2*)(xo + (size_t)b7 * DD);
        ACC_F8(accB, v0.x, v0.y); ACC_F8(accB, v1.x, v1.y);
        ACC_F8(accB, v2.x, v2.y); ACC_F8(accB, v3.x, v3.y);
        ACC_F8(accB, v4.x, v4.y); ACC_F8(accB, v5.x, v5.y);
        ACC_F8(accB, v6.x, v6.y); ACC_F8(accB, v7.x, v7.y);
        jB += 8;
    }
    while (jB + 4 <= eB) {
        int b0 = col[jB], b1 = col[jB+1], b2 = col[jB+2], b3 = col[jB+3];
        uint2 v0 = *(const uint2*)(xo + (size_t)b0 * DD);
        uint2 v1 = *(const uint2*)(xo + (size_t)b1 * DD);
        uint2 v2 = *(const uint2*)(xo + (size_t)b2 * DD);
        uint2 v3 = *(const uint2*)(xo + (size_t)b3 * DD);
        ACC_F8(accB, v0.x, v0.y); ACC_F8(accB, v1.x, v1.y);
        ACC_F8(accB, v2.x, v2.y); ACC_F8(accB, v3.x, v3.y);
        jB += 4;
    }
    if (jB + 2 <= eB) {
        int b0 = col[jB], b1 = col[jB+1];
        uint2 v0 = *(const uint2*)(xo + (size_t)b0 * DD);
        uint2 v1 = *(const uint2*)(xo + (size_t)b1 * DD);
        ACC_F8(accB, v0.x, v0.y); ACC_F8(accB, v1.x, v1.y);
        jB += 2;
    }
    if (jB < eB) {
        uint2 v = *(const uint2*)(xo + (size_t)col[jB] * DD);
        ACC_F8(accB, v.x, v.y);
    }

    // ---- segA: bf16, tree edges (short lists) ----
    while (jA + 2 <= eA) {
        int a0 = col[jA], a1 = col[jA+1];
        uint4 v0 = *(const uint4*)(xs + (size_t)a0 * DD);
        uint4 v1 = *(const uint4*)(xs + (size_t)a1 * DD);
        ACC_PAIR(aL[0], aH[0], v0.x); ACC_PAIR(aL[1], aH[1], v0.y);
        ACC_PAIR(aL[2], aH[2], v0.z); ACC_PAIR(aL[3], aH[3], v0.w);
        ACC_PAIR(aL[0], aH[0], v1.x); ACC_PAIR(aL[1], aH[1], v1.y);
        ACC_PAIR(aL[2], aH[2], v1.z); ACC_PAIR(aL[3], aH[3], v1.w);
        jA += 2;
    }
    if (jA < eA) {
        uint4 v = *(const uint4*)(xs + (size_t)col[jA] * DD);
        ACC_PAIR(aL[0], aH[0], v.x); ACC_PAIR(aL[1], aH[1], v.y);
        ACC_PAIR(aL[2], aH[2], v.z); ACC_PAIR(aL[3], aH[3], v.w);
    }

    float scA = inv[segA], scB = inv[segB];
    ushort8 rA, rB;
    #pragma unroll
    for (int t = 0; t < 4; ++t) {
        rA[2*t]   = f2b(aL[t] * scA);
        rA[2*t+1] = f2b(aH[t] * scA);
    }
    #pragma unroll
    for (int t = 0; t < 8; ++t) rB[t] = f2b(accB[t] * scB);
    *(ushort8*)(tbase)           = rA;
    *(ushort8*)(tbase + 4 * 512) = rB;
}

// ---------------- MFMA GEMM, LDS-free, swapped operands, BM=128 (4 r16 tiles/wave) -----
// mfma(W_frag, A_frag): lane holds 4 consecutive FEATURES of one node -> vector stores.
// 4 tiles/wave: 8 independent A-loads in flight; B loaded once feeds 16 MFMAs.
__global__ __launch_bounds__(256) void gemm_mfma(
    const unsigned short* __restrict__ At, const unsigned short* __restrict__ x,
    const unsigned short* __restrict__ WTt, const float* __restrict__ bc,
    void* __restrict__ outp, unsigned char* __restrict__ out8,
    int relu, int write_f32, int N, int gd)
{
    const int tid = threadIdx.x;
    const int b   = blockIdx.x;
    const int isM = (b >= gd);
    const int row0   = isM ? N + (b - gd) * BM : b * BM;
    const int rowlim = isM ? 2 * N : N;
    const int tlim   = (rowlim >> 4) - 1;

    const float* bias = bc + isM * DD;

    const int wave = tid >> 6;
    const int lane = tid & 63;
    const int wc = (wave & 1) * 64;          // 0 / 64 (feature half)
    const int fr  = lane & 15;
    const int fk8 = lane >> 4;

    int r16[4];
    #pragma unroll
    for (int t = 0; t < 4; ++t) {
        int r = (row0 >> 4) + (wave >> 1) * 4 + t;
        r16[t] = (r > tlim) ? tlim : r;
    }

    const unsigned short* Abase[4];
    const unsigned short* Xbase[4];
    #pragma unroll
    for (int t = 0; t < 4; ++t) {
        Abase[t] = At + (size_t)r16[t] * 8 * 512 + lane * 8;
        Xbase[t] = x + (size_t)(r16[t] * 16 + fr) * DD + fk8 * 8;
    }
    const unsigned short* Wbase = WTt + (size_t)isM * DD * KTOT + (size_t)(wc >> 4) * 12 * 512 + lane * 8;

    auto ldA = [&](int t, int k) -> short8 {
        return (k < 8) ? *(const short8*)(Abase[t] + k * 512)
                       : *(const short8*)(Xbase[t] + (k - 8) * 32);
    };

    floatx4 acc[4][4] = {};

    short8 aS0[4], aS1[4], aS2[4], bC[4], bN[4];
    #pragma unroll
    for (int t = 0; t < 4; ++t) { aS0[t] = ldA(t, 0); aS1[t] = ldA(t, 1); }
    #pragma unroll
    for (int c = 0; c < 4; ++c) bC[c] = *(const short8*)(Wbase + (size_t)c * 12 * 512);

    #pragma unroll
    for (int ks = 0; ks < 12; ++ks) {
        if (ks + 2 < 12) {
            #pragma unroll
            for (int t = 0; t < 4; ++t) aS2[t] = ldA(t, ks + 2);
        }
        if (ks + 1 < 12) {
            #pragma unroll
            for (int c = 0; c < 4; ++c)
                bN[c] = *(const short8*)(Wbase + (size_t)c * 12 * 512 + (ks + 1) * 512);
        }
        // swapped operands: W as A-operand (rows=features), nodes as B-operand (cols)
        #pragma unroll
        for (int c = 0; c < 4; ++c) {
            #pragma unroll
            for (int t = 0; t < 4; ++t)
                acc[t][c] = __builtin_amdgcn_mfma_f32_16x16x32_bf16(bC[c], aS0[t], acc[t][c], 0, 0, 0);
        }
        #pragma unroll
        for (int t = 0; t < 4; ++t) { aS0[t] = aS1[t]; aS1[t] = aS2[t]; }
        #pragma unroll
        for (int c = 0; c < 4; ++c) bC[c] = bN[c];
    }

    // epilogue: node = r16*16 + fr (col), feats = wc + c*16 + fk8*4 + i (rows) — vector stores
    float* outf = (float*)outp;
    unsigned short* outb = (unsigned short*)outp;
    const int rb = fk8 * 4;
    #pragma unroll
    for (int m = 0; m < 4; ++m) {
        size_t rowoff = (size_t)(r16[m] * 16 + fr) * DD;
        #pragma unroll
        for (int c = 0; c < 4; ++c) {
            int f0 = wc + c * 16 + rb;
            float4 bb = *(const float4*)(bias + f0);
            float v0 = acc[m][c][0] + bb.x;
            float v1 = acc[m][c][1] + bb.y;
            float v2 = acc[m][c][2] + bb.z;
            float v3 = acc[m][c][3] + bb.w;
            if (relu) {
                v0 = fmaxf(v0, 0.f); v1 = fmaxf(v1, 0.f);
                v2 = fmaxf(v2, 0.f); v3 = fmaxf(v3, 0.f);
            }
            if (write_f32) {
                *(float4*)(outf + rowoff + f0) = make_float4(v0, v1, v2, v3);
            } else {
                ushort4 h;
                h.x = f2b(v0); h.y = f2b(v1); h.z = f2b(v2); h.w = f2b(v3);
                *(ushort4*)(outb + rowoff + f0) = h;
                unsigned e = 0;
                e = __builtin_amdgcn_cvt_pk_fp8_f32(v0, v1, e, false);
                e = __builtin_amdgcn_cvt_pk_fp8_f32(v2, v3, e, true);
                *(unsigned*)(out8 + rowoff + f0) = e;
            }
        }
    }
}

extern "C" void kernel_launch(void* const* d_in, const int* in_sizes, int n_in,
                              void* d_out, int out_size, void* d_ws, size_t ws_size,
                              hipStream_t stream)
{
    const float* x_d = (const float*)d_in[0];
    const float* x_m = (const float*)d_in[1];
    const float* Wl  = (const float*)d_in[6];
    const float* bl  = (const float*)d_in[7];
    const float* Wr  = (const float*)d_in[8];
    float* out = (float*)d_out;

    const int N    = in_sizes[0] / DD;
    const int E_dd = in_sizes[2] / 2;
    const int E_mm = in_sizes[3] / 2;
    const int E_dm = in_sizes[4] / 2;
    const int E_md = in_sizes[5] / 2;
    const int E_tot = E_dd + E_md + E_mm + E_dm;
    const int n4 = 4 * N;
    const int nb = (n4 + BS - 1) >> BS_BITS;
    const int M16 = (2 * N + 15) >> 4;

    char* ws = (char*)d_ws;
    size_t off = 0;
    auto alloc = [&](size_t bytes) {
        void* p = ws + off;
        off += (bytes + 255) & ~(size_t)255;
        return p;
    };
    unsigned short* xb   = (unsigned short*)alloc((size_t)2 * N * DD * 2);  // [xd|xm] bf16
    unsigned short* hb   = (unsigned short*)alloc((size_t)2 * N * DD * 2);  // [hd|hm] bf16
    unsigned char*  x8   = (unsigned char*) alloc((size_t)2 * N * DD);      // fp8 mirror of x
    unsigned char*  h8   = (unsigned char*) alloc((size_t)2 * N * DD);      // fp8 mirror of h
    unsigned short* At   = (unsigned short*)alloc((size_t)M16 * 8 * 512 * 2);
    float* inv_all = (float*)alloc((size_t)n4 * 4);
    int*   rp_all  = (int*)  alloc((size_t)(n4 + 1) * 4);
    int*   bucket_fill = (int*)alloc((size_t)NBMAX * 4);
    int*   bucket_base = (int*)alloc((size_t)NBMAX * 4);
    unsigned short* WTt = (unsigned short*)alloc((size_t)2 * 2 * DD * KTOT * 2);
    float* bc      = (float*)alloc((size_t)512 * 4);
    unsigned* stage = (unsigned*)alloc((size_t)nb * CAP * 4);
    int*   col     = (int*)alloc((size_t)E_tot * 4);
    unsigned long long* ovf = (unsigned long long*)alloc((size_t)(1 << 18) * 8);
    int*   ovf_cnt = (int*)alloc(256);
    int*   flag    = (int*)alloc(256);

    // ---- edge dtype probe ----
    hipMemsetAsync(flag, 0, 256, stream);
    detect_i32<<<4, 256, 0, stream>>>((const int*)d_in[2], 1024, flag);

    // ---- x -> bf16 + fp8 mirror ([xd|xm] contiguous) ----
    const int n8 = N * DD / 8;
    cvt_bf16<<<(n8 + 255) / 256, 256, 0, stream>>>(x_d, xb, x8, n8);
    cvt_bf16<<<(n8 + 255) / 256, 256, 0, stream>>>(x_m, xb + (size_t)N * DD,
                                                   x8 + (size_t)N * DD, n8);

    // ---- CSR build: bin -> bucket scan -> per-bucket count/scan/fill ----
    hipMemsetAsync(bucket_fill, 0, (size_t)NBMAX * 4, stream);
    hipMemsetAsync(ovf_cnt, 0, 256, stream);
    const int nchunks = (E_tot + CHUNK - 1) / CHUNK;
    bin_edges<<<nchunks, 512, 0, stream>>>(
        d_in[2], d_in[5], d_in[3], d_in[4], E_dd, E_md, E_mm, E_dm,
        flag, bucket_fill, stage, ovf, ovf_cnt, N, nb);
    scan_buckets<<<1, 512, 0, stream>>>(bucket_fill, nb, bucket_base);
    fill_from_stage<<<nb, 512, 0, stream>>>(
        stage, bucket_fill, bucket_base, ovf, ovf_cnt, rp_all, inv_all, col, n4);

    build_wcomb<<<(2 * 2 * DD * KTOT + 255) / 256, 256, 0, stream>>>(Wl, bl, Wr, WTt, bc);

    const int agg_grid = (int)(((size_t)2 * N * 16 + 255) / 256);
    const int gd = (N + BM - 1) / BM;
    const int gemm_grid = 2 * gd;
    const unsigned short* xcur = xb;
    const unsigned char*  xcur8 = x8;
    for (int l = 0; l < 2; ++l) {
        int relu = (l == 0);
        int wf32 = (l == 1);
        void* ob = (l == 1) ? (void*)out : (void*)hb;

        aggregate_all<<<agg_grid, 256, 0, stream>>>(xcur, xcur8, rp_all, inv_all, col, At, N);
        gemm_mfma<<<gemm_grid, 256, 0, stream>>>(
            At, xcur, WTt + (size_t)l * 2 * DD * KTOT, bc + l * 2 * DD,
            ob, h8, relu, wf32, N, gd);

        xcur = hb;
        xcur8 = h8;
    }
}

// Round 21
// 392.027 us; speedup vs baseline: 1.0064x; 1.0064x over previous
//
#include <hip/hip_runtime.h>

#define DD 128
#define KTOT 384
#define BM 128
#define BS_BITS 10
#define BS 1024          // nodes per bucket
#define NBMAX 512        // max buckets (4N <= 512K)
#define CHUNK 2048       // edges per bin_edges block
#define CAP 12288        // stage slots per bucket (max expected ~10.6K)

typedef __attribute__((ext_vector_type(8))) short short8;
typedef __attribute__((ext_vector_type(8))) unsigned short ushort8;
typedef __attribute__((ext_vector_type(4))) float floatx4;
typedef __attribute__((ext_vector_type(2))) float floatx2;

__device__ __forceinline__ unsigned short f2b(float f) {
    union { float f; unsigned u; } v; v.f = f;
    return (unsigned short)((v.u + 0x7fffu + ((v.u >> 16) & 1u)) >> 16);
}
__device__ __forceinline__ float b2f(unsigned short u) {
    union { unsigned u; float f; } v; v.u = ((unsigned)u) << 16;
    return v.f;
}
__device__ __forceinline__ float asf(unsigned u) {
    union { unsigned u; float f; } v; v.u = u; return v.f;
}

// bf16 pair-accumulate: u32 = (bf16_hi<<16)|bf16_lo (R16-verified)
#define ACC_PAIR(accL, accH, u) { accH += asf(u); accL += asf((u) << 16); }

// decode 8 fp8 (e4m3) from uint2 and accumulate into acc[8] — HW packed cvt
#define ACC_F8(acc, ux, uy) { \
    floatx2 p0 = __builtin_amdgcn_cvt_pk_f32_fp8((ux), false); \
    floatx2 p1 = __builtin_amdgcn_cvt_pk_f32_fp8((ux), true);  \
    floatx2 p2 = __builtin_amdgcn_cvt_pk_f32_fp8((uy), false); \
    floatx2 p3 = __builtin_amdgcn_cvt_pk_f32_fp8((uy), true);  \
    acc[0] += p0.x; acc[1] += p0.y; acc[2] += p1.x; acc[3] += p1.y; \
    acc[4] += p2.x; acc[5] += p2.y; acc[6] += p3.x; acc[7] += p3.y; }

// ---------------- edge dtype probe: int64 arrays have all-zero odd int32 words ----------
__global__ __launch_bounds__(256) void detect_i32(const int* __restrict__ p, int nodd,
                                                  int* __restrict__ flag)
{
    int i = blockIdx.x * 256 + threadIdx.x;
    if (i < nodd && p[2 * i + 1] != 0) atomicOr(flag, 1);
}

// ---------------- x -> bf16 (row-major) + fp8 gather mirror ----------------
__global__ __launch_bounds__(256) void cvt_bf16(const float* __restrict__ in,
                                                unsigned short* __restrict__ out,
                                                unsigned char* __restrict__ out8, int n8)
{
    int i = blockIdx.x * 256 + threadIdx.x;
    if (i >= n8) return;
    float4 v0 = *(const float4*)(in + (size_t)i * 8);
    float4 v1 = *(const float4*)(in + (size_t)i * 8 + 4);
    ushort8 r;
    r[0]=f2b(v0.x); r[1]=f2b(v0.y); r[2]=f2b(v0.z); r[3]=f2b(v0.w);
    r[4]=f2b(v1.x); r[5]=f2b(v1.y); r[6]=f2b(v1.z); r[7]=f2b(v1.w);
    *(ushort8*)(out + (size_t)i * 8) = r;
    unsigned a = 0, b = 0;
    a = __builtin_amdgcn_cvt_pk_fp8_f32(v0.x, v0.y, a, false);
    a = __builtin_amdgcn_cvt_pk_fp8_f32(v0.z, v0.w, a, true);
    b = __builtin_amdgcn_cvt_pk_fp8_f32(v1.x, v1.y, b, false);
    b = __builtin_amdgcn_cvt_pk_fp8_f32(v1.z, v1.w, b, true);
    *(uint2*)(out8 + (size_t)i * 8) = make_uint2(a, b);
}

// ---------------- weight prep: WT_t = combined W^T in fragment-tiled layout ------------
__global__ __launch_bounds__(256) void build_wcomb(
    const float* __restrict__ Wl, const float* __restrict__ bl,
    const float* __restrict__ Wr, unsigned short* __restrict__ WTt, float* __restrict__ bc)
{
    int idx = blockIdx.x * 256 + threadIdx.x;
    if (idx < 2 * 2 * DD * KTOT) {
        int k  = idx % KTOT;
        int t1 = idx / KTOT;
        int i  = t1 & 127;
        int t2 = t1 >> 7;
        int dt = t2 & 1;      // 0 = dst d, 1 = dst m
        int l  = t2 >> 1;
        int ta = dt ? 1 : 0;  // d: dd(0), m: mm(1)
        int tb = dt ? 2 : 3;  // d: md(3), m: dm(2)
        float v;
        if (k < 128) {
            v = Wl[(((size_t)(l * 4 + ta) * 128 + i) << 7) + k];
        } else if (k < 256) {
            v = Wl[(((size_t)(l * 4 + tb) * 128 + i) << 7) + (k - 128)];
        } else {
            int kk = k - 256;
            v = Wr[(((size_t)(l * 4 + ta) * 128 + i) << 7) + kk]
              + Wr[(((size_t)(l * 4 + tb) * 128 + i) << 7) + kk];
        }
        int tidx = ((((i >> 4) * 12 + (k >> 5)) * 64) + (((k >> 3) & 3) * 16 + (i & 15))) * 8
                 + (k & 7);
        WTt[(size_t)t2 * (DD * KTOT) + tidx] = f2b(v);
    }
    if (idx < 512) {
        int i  = idx & 127;
        int t2 = idx >> 7;
        int dt = t2 & 1;
        int l  = t2 >> 1;
        int ta = dt ? 1 : 0;
        int tb = dt ? 2 : 3;
        bc[idx] = bl[(l * 4 + ta) * 128 + i] + bl[(l * 4 + tb) * 128 + i];
    }
}

// ---------------- phase A: LDS-binned edge staging, fixed-CAP bucket regions ----------
__global__ __launch_bounds__(512) void bin_edges(
    const void* __restrict__ e0, const void* __restrict__ e1,
    const void* __restrict__ e2, const void* __restrict__ e3,
    int E0, int E1, int E2, int E3,
    const int* __restrict__ flag, int* __restrict__ bucket_fill,
    unsigned* __restrict__ stage,
    unsigned long long* __restrict__ ovf, int* __restrict__ ovf_cnt,
    int N, int nb)
{
    __shared__ unsigned sb_pack[CHUNK];
    __shared__ unsigned short sb_b[CHUNK];
    __shared__ int hist[NBMAX];
    __shared__ int offs[NBMAX];
    __shared__ int base[NBMAX];

    const int tid   = threadIdx.x;
    const int E_tot = E0 + E1 + E2 + E3;
    const int e_bas = blockIdx.x * CHUNK;
    const int e_end = min(e_bas + CHUNK, E_tot);
    const int cnt_e = e_end - e_bas;
    const int isI32 = *flag;

    for (int i = tid; i < nb; i += 512) hist[i] = 0;
    __syncthreads();

    unsigned my_pack[4];
    int my_b[4], my_r[4];
    #pragma unroll
    for (int u = 0; u < 4; ++u) {
        my_b[u] = -1;
        int e = e_bas + tid + u * 512;
        if (e < e_end) {
            const void* ep; int El, type, le = e;
            if (le < E0)              { ep = e0; El = E0; type = 0; }
            else if ((le -= E0) < E1) { ep = e1; El = E1; type = 1; }
            else if ((le -= E1) < E2) { ep = e2; El = E2; type = 2; }
            else                      { le -= E2; ep = e3; El = E3; type = 3; }
            int s, d;
            if (isI32) {
                s = ((const int*)ep)[le];
                d = ((const int*)ep)[(size_t)El + le];
            } else {
                s = (int)((const long long*)ep)[le];
                d = (int)((const long long*)ep)[(size_t)El + le];
            }
            int gnode = type * N + d;
            int b = gnode >> BS_BITS;
            my_b[u]    = b;
            my_pack[u] = ((unsigned)s << BS_BITS) | (unsigned)(gnode & (BS - 1));
            my_r[u]    = atomicAdd(&hist[b], 1);
        }
    }
    __syncthreads();

    offs[tid] = (tid < nb) ? hist[tid] : 0;
    __syncthreads();
    for (int d = 1; d < 512; d <<= 1) {
        int v = (tid >= d) ? offs[tid - d] : 0;
        __syncthreads();
        offs[tid] += v;
        __syncthreads();
    }
    if (tid < nb) {
        offs[tid] -= hist[tid];                              // exclusive
        base[tid] = hist[tid] ? atomicAdd(&bucket_fill[tid], hist[tid]) : 0;
    }
    __syncthreads();

    #pragma unroll
    for (int u = 0; u < 4; ++u) {
        if (my_b[u] >= 0) {
            int pos = offs[my_b[u]] + my_r[u];
            sb_pack[pos] = my_pack[u];
            sb_b[pos]    = (unsigned short)my_b[u];
        }
    }
    __syncthreads();

    for (int pos = tid; pos < cnt_e; pos += 512) {
        int b = sb_b[pos];
        unsigned p = sb_pack[pos];
        int idx = base[b] + (pos - offs[b]);
        if (idx < CAP) {
            stage[(size_t)b * CAP + idx] = p;
        } else {                                             // overflow (expected: never)
            int k = atomicAdd(ovf_cnt, 1);
            int gnode = (b << BS_BITS) | (int)(p & (BS - 1));
            ovf[k] = ((unsigned long long)(unsigned)gnode << 32) | (p >> BS_BITS);
        }
    }
}

// ---------------- exclusive scan over bucket totals (1 block) ----------------
__global__ __launch_bounds__(512) void scan_buckets(const int* __restrict__ fill, int nb,
                                                    int* __restrict__ base)
{
    __shared__ int s[512];
    const int tid = threadIdx.x;
    int v = (tid < nb) ? fill[tid] : 0;
    s[tid] = v;
    __syncthreads();
    for (int d = 1; d < 512; d <<= 1) {
        int u = (tid >= d) ? s[tid - d] : 0;
        __syncthreads();
        s[tid] += u;
        __syncthreads();
    }
    if (tid < nb) base[tid] = s[tid] - v;    // exclusive
}

// ---------------- phase B: per-bucket count + scan + rp/inv + CSR fill ----------------
__global__ __launch_bounds__(512) void fill_from_stage(
    const unsigned* __restrict__ stage, const int* __restrict__ bucket_fill,
    const int* __restrict__ bucket_base,
    const unsigned long long* __restrict__ ovf, const int* __restrict__ ovf_cnt,
    int* __restrict__ rp_all, float* __restrict__ inv_all, int* __restrict__ col, int n4)
{
    __shared__ int cl[BS];     // counts, later cursors
    __shared__ int rl[BS];     // exclusive scan
    __shared__ int w[512];

    const int tid   = threadIdx.x;
    const int b     = blockIdx.x;
    const int node0 = b << BS_BITS;
    const int nn    = min(BS, n4 - node0);

    cl[tid] = 0; cl[tid + 512] = 0;
    __syncthreads();

    const int total  = bucket_fill[b];
    const int nstage = min(total, CAP);
    const unsigned* st = stage + (size_t)b * CAP;
    const int novf = *ovf_cnt;

    for (int j = tid; j < nstage; j += 512)
        atomicAdd(&cl[st[j] & (BS - 1)], 1);
    for (int k = tid; k < novf; k += 512) {
        int g = (int)(ovf[k] >> 32);
        if (g >= node0 && g < node0 + nn) atomicAdd(&cl[g - node0], 1);
    }
    __syncthreads();

    int a0 = cl[2 * tid], a1 = cl[2 * tid + 1];
    w[tid] = a0 + a1;
    __syncthreads();
    for (int d = 1; d < 512; d <<= 1) {
        int v = (tid >= d) ? w[tid - d] : 0;
        __syncthreads();
        w[tid] += v;
        __syncthreads();
    }
    int excl = w[tid] - a0 - a1;
    rl[2 * tid]     = excl;
    rl[2 * tid + 1] = excl + a0;
    __syncthreads();

    const int gbase = bucket_base[b];
    for (int i = tid; i < nn; i += 512) {
        rp_all[node0 + i] = gbase + rl[i];
        inv_all[node0 + i] = 1.0f / (float)max(cl[i], 1);
    }
    if (b == gridDim.x - 1 && tid == 0) rp_all[n4] = gbase + total;
    __syncthreads();

    for (int i = tid; i < BS; i += 512) cl[i] = gbase + rl[i];
    __syncthreads();

    for (int j = tid; j < nstage; j += 512) {
        unsigned p = st[j];
        int slot = atomicAdd(&cl[p & (BS - 1)], 1);
        col[slot] = (int)(p >> BS_BITS);
    }
    for (int k = tid; k < novf; k += 512) {
        unsigned long long p = ovf[k];
        int g = (int)(p >> 32);
        if (g >= node0 && g < node0 + nn) {
            int slot = atomicAdd(&cl[g - node0], 1);
            col[slot] = (int)(p & 0xffffffffu);
        }
    }
}

// ---------------- gather-aggregate BOTH dst types into fragment-tiled A_t ----------------
// MIXED precision: segA (tree, deg~1, no error averaging) gathers bf16 x;
//                  segB (link, deg~10, mean smooths fp8 noise) gathers fp8 x8.
__global__ __launch_bounds__(256) void aggregate_all(
    const unsigned short* __restrict__ x, const unsigned char* __restrict__ x8,
    const int* __restrict__ rp, const float* __restrict__ inv,
    const int* __restrict__ col, unsigned short* __restrict__ At, int N)
{
    long long g = (long long)blockIdx.x * 256 + threadIdx.x;
    int node = (int)(g >> 4);
    int q    = (int)(g & 15);          // lane: 8 elems (16 B bf16 / 8 B fp8)
    if (node >= 2 * N) return;

    const int isM  = node >= N;
    const int segA = node + (isM ? N : 0);
    const int segB = segA + N;
    const int selfbase  = isM ? N : 0;
    const int otherbase = N - selfbase;

    const int r16 = node >> 4;
    const int fr  = node & 15;
    unsigned short* tbase = At + ((size_t)r16 * 8 + (q >> 2)) * 512 + ((q & 3) * 16 + fr) * 8;

    const unsigned short* xs = x  + (size_t)selfbase  * DD + q * 8;   // bf16 self
    const unsigned char*  xo = x8 + (size_t)otherbase * DD + q * 8;   // fp8 other

    float aL[4], aH[4], accB[8];
    #pragma unroll
    for (int t = 0; t < 4; ++t) { aL[t]=0.f; aH[t]=0.f; }
    #pragma unroll
    for (int t = 0; t < 8; ++t) accB[t] = 0.f;

    int jA = rp[segA], eA = rp[segA + 1];
    int jB = rp[segB], eB = rp[segB + 1];

    // ---- segB: fp8, 8-deep independent loads ----
    while (jB + 8 <= eB) {
        int b0 = col[jB],   b1 = col[jB+1], b2 = col[jB+2], b3 = col[jB+3];
        int b4 = col[jB+4], b5 = col[jB+5], b6 = col[jB+6], b7 = col[jB+7];
        uint2 v0 = *(const uint2*)(xo + (size_t)b0 * DD);
        uint2 v1 = *(const uint2*)(xo + (size_t)b1 * DD);
        uint2 v2 = *(const uint2*)(xo + (size_t)b2 * DD);
        uint2 v3 = *(const uint2*)(xo + (size_t)b3 * DD);
        uint2 v4 = *(const uint2*)(xo + (size_t)b4 * DD);
        uint2 v5 = *(const uint2*)(xo + (size_t)b5 * DD);
        uint2 v6 = *(const uint2*)(xo + (size_t)b6 * DD);
        uint2 v7 = *(const uint2*)(xo + (size_t)b7 * DD);
        ACC_F8(accB, v0.x, v0.y); ACC_F8(accB, v1.x, v1.y);
        ACC_F8(accB, v2.x, v2.y); ACC_F8(accB, v3.x, v3.y);
        ACC_F8(accB, v4.x, v4.y); ACC_F8(accB, v5.x, v5.y);
        ACC_F8(accB, v6.x, v6.y); ACC_F8(accB, v7.x, v7.y);
        jB += 8;
    }
    while (jB + 4 <= eB) {
        int b0 = col[jB], b1 = col[jB+1], b2 = col[jB+2], b3 = col[jB+3];
        uint2 v0 = *(const uint2*)(xo + (size_t)b0 * DD);
        uint2 v1 = *(const uint2*)(xo + (size_t)b1 * DD);
        uint2 v2 = *(const uint2*)(xo + (size_t)b2 * DD);
        uint2 v3 = *(const uint2*)(xo + (size_t)b3 * DD);
        ACC_F8(accB, v0.x, v0.y); ACC_F8(accB, v1.x, v1.y);
        ACC_F8(accB, v2.x, v2.y); ACC_F8(accB, v3.x, v3.y);
        jB += 4;
    }
    if (jB + 2 <= eB) {
        int b0 = col[jB], b1 = col[jB+1];
        uint2 v0 = *(const uint2*)(xo + (size_t)b0 * DD);
        uint2 v1 = *(const uint2*)(xo + (size_t)b1 * DD);
        ACC_F8(accB, v0.x, v0.y); ACC_F8(accB, v1.x, v1.y);
        jB += 2;
    }
    if (jB < eB) {
        uint2 v = *(const uint2*)(xo + (size_t)col[jB] * DD);
        ACC_F8(accB, v.x, v.y);
    }

    // ---- segA: bf16, tree edges (short lists) ----
    while (jA + 2 <= eA) {
        int a0 = col[jA], a1 = col[jA+1];
        uint4 v0 = *(const uint4*)(xs + (size_t)a0 * DD);
        uint4 v1 = *(const uint4*)(xs + (size_t)a1 * DD);
        ACC_PAIR(aL[0], aH[0], v0.x); ACC_PAIR(aL[1], aH[1], v0.y);
        ACC_PAIR(aL[2], aH[2], v0.z); ACC_PAIR(aL[3], aH[3], v0.w);
        ACC_PAIR(aL[0], aH[0], v1.x); ACC_PAIR(aL[1], aH[1], v1.y);
        ACC_PAIR(aL[2], aH[2], v1.z); ACC_PAIR(aL[3], aH[3], v1.w);
        jA += 2;
    }
    if (jA < eA) {
        uint4 v = *(const uint4*)(xs + (size_t)col[jA] * DD);
        ACC_PAIR(aL[0], aH[0], v.x); ACC_PAIR(aL[1], aH[1], v.y);
        ACC_PAIR(aL[2], aH[2], v.z); ACC_PAIR(aL[3], aH[3], v.w);
    }

    float scA = inv[segA], scB = inv[segB];
    ushort8 rA, rB;
    #pragma unroll
    for (int t = 0; t < 4; ++t) {
        rA[2*t]   = f2b(aL[t] * scA);
        rA[2*t+1] = f2b(aH[t] * scA);
    }
    #pragma unroll
    for (int t = 0; t < 8; ++t) rB[t] = f2b(accB[t] * scB);
    *(ushort8*)(tbase)           = rA;
    *(ushort8*)(tbase + 4 * 512) = rB;
}

// ---------------- MFMA GEMM, LDS-free, swapped operands, BM=128 (4 r16 tiles/wave) -----
// mfma(W_frag, A_frag): lane holds 4 consecutive FEATURES of one node -> vector stores.
// 4 tiles/wave: 8 independent A-loads in flight; B loaded once feeds 16 MFMAs.
__global__ __launch_bounds__(256) void gemm_mfma(
    const unsigned short* __restrict__ At, const unsigned short* __restrict__ x,
    const unsigned short* __restrict__ WTt, const float* __restrict__ bc,
    void* __restrict__ outp, unsigned char* __restrict__ out8,
    int relu, int write_f32, int N, int gd)
{
    const int tid = threadIdx.x;
    const int b   = blockIdx.x;
    const int isM = (b >= gd);
    const int row0   = isM ? N + (b - gd) * BM : b * BM;
    const int rowlim = isM ? 2 * N : N;
    const int tlim   = (rowlim >> 4) - 1;

    const float* bias = bc + isM * DD;

    const int wave = tid >> 6;
    const int lane = tid & 63;
    const int wc = (wave & 1) * 64;          // 0 / 64 (feature half)
    const int fr  = lane & 15;
    const int fk8 = lane >> 4;

    int r16[4];
    #pragma unroll
    for (int t = 0; t < 4; ++t) {
        int r = (row0 >> 4) + (wave >> 1) * 4 + t;
        r16[t] = (r > tlim) ? tlim : r;
    }

    const unsigned short* Abase[4];
    const unsigned short* Xbase[4];
    #pragma unroll
    for (int t = 0; t < 4; ++t) {
        Abase[t] = At + (size_t)r16[t] * 8 * 512 + lane * 8;
        Xbase[t] = x + (size_t)(r16[t] * 16 + fr) * DD + fk8 * 8;
    }
    const unsigned short* Wbase = WTt + (size_t)isM * DD * KTOT + (size_t)(wc >> 4) * 12 * 512 + lane * 8;

    auto ldA = [&](int t, int k) -> short8 {
        return (k < 8) ? *(const short8*)(Abase[t] + k * 512)
                       : *(const short8*)(Xbase[t] + (k - 8) * 32);
    };

    floatx4 acc[4][4] = {};

    short8 aS0[4], aS1[4], aS2[4], bC[4], bN[4];
    #pragma unroll
    for (int t = 0; t < 4; ++t) { aS0[t] = ldA(t, 0); aS1[t] = ldA(t, 1); }
    #pragma unroll
    for (int c = 0; c < 4; ++c) bC[c] = *(const short8*)(Wbase + (size_t)c * 12 * 512);

    #pragma unroll
    for (int ks = 0; ks < 12; ++ks) {
        if (ks + 2 < 12) {
            #pragma unroll
            for (int t = 0; t < 4; ++t) aS2[t] = ldA(t, ks + 2);
        }
        if (ks + 1 < 12) {
            #pragma unroll
            for (int c = 0; c < 4; ++c)
                bN[c] = *(const short8*)(Wbase + (size_t)c * 12 * 512 + (ks + 1) * 512);
        }
        // swapped operands: W as A-operand (rows=features), nodes as B-operand (cols)
        #pragma unroll
        for (int c = 0; c < 4; ++c) {
            #pragma unroll
            for (int t = 0; t < 4; ++t)
                acc[t][c] = __builtin_amdgcn_mfma_f32_16x16x32_bf16(bC[c], aS0[t], acc[t][c], 0, 0, 0);
        }
        #pragma unroll
        for (int t = 0; t < 4; ++t) { aS0[t] = aS1[t]; aS1[t] = aS2[t]; }
        #pragma unroll
        for (int c = 0; c < 4; ++c) bC[c] = bN[c];
    }

    // epilogue: node = r16*16 + fr (col), feats = wc + c*16 + fk8*4 + i (rows) — vector stores
    float* outf = (float*)outp;
    unsigned short* outb = (unsigned short*)outp;
    const int rb = fk8 * 4;
    #pragma unroll
    for (int m = 0; m < 4; ++m) {
        size_t rowoff = (size_t)(r16[m] * 16 + fr) * DD;
        #pragma unroll
        for (int c = 0; c < 4; ++c) {
            int f0 = wc + c * 16 + rb;
            float4 bb = *(const float4*)(bias + f0);
            float v0 = acc[m][c][0] + bb.x;
            float v1 = acc[m][c][1] + bb.y;
            float v2 = acc[m][c][2] + bb.z;
            float v3 = acc[m][c][3] + bb.w;
            if (relu) {
                v0 = fmaxf(v0, 0.f); v1 = fmaxf(v1, 0.f);
                v2 = fmaxf(v2, 0.f); v3 = fmaxf(v3, 0.f);
            }
            if (write_f32) {
                *(float4*)(outf + rowoff + f0) = make_float4(v0, v1, v2, v3);
            } else {
                ushort4 h;
                h.x = f2b(v0); h.y = f2b(v1); h.z = f2b(v2); h.w = f2b(v3);
                *(ushort4*)(outb + rowoff + f0) = h;
                unsigned e = 0;
                e = __builtin_amdgcn_cvt_pk_fp8_f32(v0, v1, e, false);
                e = __builtin_amdgcn_cvt_pk_fp8_f32(v2, v3, e, true);
                *(unsigned*)(out8 + rowoff + f0) = e;
            }
        }
    }
}

extern "C" void kernel_launch(void* const* d_in, const int* in_sizes, int n_in,
                              void* d_out, int out_size, void* d_ws, size_t ws_size,
                              hipStream_t stream)
{
    const float* x_d = (const float*)d_in[0];
    const float* x_m = (const float*)d_in[1];
    const float* Wl  = (const float*)d_in[6];
    const float* bl  = (const float*)d_in[7];
    const float* Wr  = (const float*)d_in[8];
    float* out = (float*)d_out;

    const int N    = in_sizes[0] / DD;
    const int E_dd = in_sizes[2] / 2;
    const int E_mm = in_sizes[3] / 2;
    const int E_dm = in_sizes[4] / 2;
    const int E_md = in_sizes[5] / 2;
    const int E_tot = E_dd + E_md + E_mm + E_dm;
    const int n4 = 4 * N;
    const int nb = (n4 + BS - 1) >> BS_BITS;
    const int M16 = (2 * N + 15) >> 4;

    char* ws = (char*)d_ws;
    size_t off = 0;
    auto alloc = [&](size_t bytes) {
        void* p = ws + off;
        off += (bytes + 255) & ~(size_t)255;
        return p;
    };
    unsigned short* xb   = (unsigned short*)alloc((size_t)2 * N * DD * 2);  // [xd|xm] bf16
    unsigned short* hb   = (unsigned short*)alloc((size_t)2 * N * DD * 2);  // [hd|hm] bf16
    unsigned char*  x8   = (unsigned char*) alloc((size_t)2 * N * DD);      // fp8 mirror of x
    unsigned char*  h8   = (unsigned char*) alloc((size_t)2 * N * DD);      // fp8 mirror of h
    unsigned short* At   = (unsigned short*)alloc((size_t)M16 * 8 * 512 * 2);
    float* inv_all = (float*)alloc((size_t)n4 * 4);
    int*   rp_all  = (int*)  alloc((size_t)(n4 + 1) * 4);
    int*   bucket_fill = (int*)alloc((size_t)NBMAX * 4);
    int*   bucket_base = (int*)alloc((size_t)NBMAX * 4);
    unsigned short* WTt = (unsigned short*)alloc((size_t)2 * 2 * DD * KTOT * 2);
    float* bc      = (float*)alloc((size_t)512 * 4);
    unsigned* stage = (unsigned*)alloc((size_t)nb * CAP * 4);
    int*   col     = (int*)alloc((size_t)E_tot * 4);
    unsigned long long* ovf = (unsigned long long*)alloc((size_t)(1 << 18) * 8);
    int*   ovf_cnt = (int*)alloc(256);
    int*   flag    = (int*)alloc(256);

    // ---- edge dtype probe ----
    hipMemsetAsync(flag, 0, 256, stream);
    detect_i32<<<4, 256, 0, stream>>>((const int*)d_in[2], 1024, flag);

    // ---- x -> bf16 + fp8 mirror ([xd|xm] contiguous) ----
    const int n8 = N * DD / 8;
    cvt_bf16<<<(n8 + 255) / 256, 256, 0, stream>>>(x_d, xb, x8, n8);
    cvt_bf16<<<(n8 + 255) / 256, 256, 0, stream>>>(x_m, xb + (size_t)N * DD,
                                                   x8 + (size_t)N * DD, n8);

    // ---- CSR build: bin -> bucket scan -> per-bucket count/scan/fill ----
    hipMemsetAsync(bucket_fill, 0, (size_t)NBMAX * 4, stream);
    hipMemsetAsync(ovf_cnt, 0, 256, stream);
    const int nchunks = (E_tot + CHUNK - 1) / CHUNK;
    bin_edges<<<nchunks, 512, 0, stream>>>(
        d_in[2], d_in[5], d_in[3], d_in[4], E_dd, E_md, E_mm, E_dm,
        flag, bucket_fill, stage, ovf, ovf_cnt, N, nb);
    scan_buckets<<<1, 512, 0, stream>>>(bucket_fill, nb, bucket_base);
    fill_from_stage<<<nb, 512, 0, stream>>>(
        stage, bucket_fill, bucket_base, ovf, ovf_cnt, rp_all, inv_all, col, n4);

    build_wcomb<<<(2 * 2 * DD * KTOT + 255) / 256, 256, 0, stream>>>(Wl, bl, Wr, WTt, bc);

    const int agg_grid = (int)(((size_t)2 * N * 16 + 255) / 256);
    const int gd = (N + BM - 1) / BM;
    const int gemm_grid = 2 * gd;
    const unsigned short* xcur = xb;
    const unsigned char*  xcur8 = x8;
    for (int l = 0; l < 2; ++l) {
        int relu = (l == 0);
        int wf32 = (l == 1);
        void* ob = (l == 1) ? (void*)out : (void*)hb;

        aggregate_all<<<agg_grid, 256, 0, stream>>>(xcur, xcur8, rp_all, inv_all, col, At, N);
        gemm_mfma<<<gemm_grid, 256, 0, stream>>>(
            At, xcur, WTt + (size_t)l * 2 * DD * KTOT, bc + l * 2 * DD,
            ob, h8, relu, wf32, N, gd);

        xcur = hb;
        xcur8 = h8;
    }
}

// Round 22
// 372.725 us; speedup vs baseline: 1.0585x; 1.0518x over previous
//
#include <hip/hip_runtime.h>

#define DD 128
#define KTOT 384
#define BM 64
#define BS_BITS 10
#define BS 1024          // nodes per bucket
#define NBMAX 512        // max buckets (4N <= 512K)
#define CHUNK 2048       // edges per bin_edges block
#define CAP 12288        // stage slots per bucket (max expected ~10.6K)

typedef __attribute__((ext_vector_type(8))) short short8;
typedef __attribute__((ext_vector_type(8))) unsigned short ushort8;
typedef __attribute__((ext_vector_type(4))) float floatx4;
typedef __attribute__((ext_vector_type(2))) float floatx2;

__device__ __forceinline__ unsigned short f2b(float f) {
    union { float f; unsigned u; } v; v.f = f;
    return (unsigned short)((v.u + 0x7fffu + ((v.u >> 16) & 1u)) >> 16);
}
__device__ __forceinline__ float b2f(unsigned short u) {
    union { unsigned u; float f; } v; v.u = ((unsigned)u) << 16;
    return v.f;
}
__device__ __forceinline__ float asf(unsigned u) {
    union { unsigned u; float f; } v; v.u = u; return v.f;
}

// bf16 pair-accumulate: u32 = (bf16_hi<<16)|bf16_lo (R16-verified)
#define ACC_PAIR(accL, accH, u) { accH += asf(u); accL += asf((u) << 16); }

// decode 8 fp8 (e4m3) from uint2 and accumulate into acc[8] — HW packed cvt
#define ACC_F8(acc, ux, uy) { \
    floatx2 p0 = __builtin_amdgcn_cvt_pk_f32_fp8((ux), false); \
    floatx2 p1 = __builtin_amdgcn_cvt_pk_f32_fp8((ux), true);  \
    floatx2 p2 = __builtin_amdgcn_cvt_pk_f32_fp8((uy), false); \
    floatx2 p3 = __builtin_amdgcn_cvt_pk_f32_fp8((uy), true);  \
    acc[0] += p0.x; acc[1] += p0.y; acc[2] += p1.x; acc[3] += p1.y; \
    acc[4] += p2.x; acc[5] += p2.y; acc[6] += p3.x; acc[7] += p3.y; }

// ---------------- edge dtype probe: int64 arrays have all-zero odd int32 words ----------
__global__ __launch_bounds__(256) void detect_i32(const int* __restrict__ p, int nodd,
                                                  int* __restrict__ flag)
{
    int i = blockIdx.x * 256 + threadIdx.x;
    if (i < nodd && p[2 * i + 1] != 0) atomicOr(flag, 1);
}

// ---------------- x -> bf16 (row-major) + fp8 gather mirror ----------------
__global__ __launch_bounds__(256) void cvt_bf16(const float* __restrict__ in,
                                                unsigned short* __restrict__ out,
                                                unsigned char* __restrict__ out8, int n8)
{
    int i = blockIdx.x * 256 + threadIdx.x;
    if (i >= n8) return;
    float4 v0 = *(const float4*)(in + (size_t)i * 8);
    float4 v1 = *(const float4*)(in + (size_t)i * 8 + 4);
    ushort8 r;
    r[0]=f2b(v0.x); r[1]=f2b(v0.y); r[2]=f2b(v0.z); r[3]=f2b(v0.w);
    r[4]=f2b(v1.x); r[5]=f2b(v1.y); r[6]=f2b(v1.z); r[7]=f2b(v1.w);
    *(ushort8*)(out + (size_t)i * 8) = r;
    unsigned a = 0, b = 0;
    a = __builtin_amdgcn_cvt_pk_fp8_f32(v0.x, v0.y, a, false);
    a = __builtin_amdgcn_cvt_pk_fp8_f32(v0.z, v0.w, a, true);
    b = __builtin_amdgcn_cvt_pk_fp8_f32(v1.x, v1.y, b, false);
    b = __builtin_amdgcn_cvt_pk_fp8_f32(v1.z, v1.w, b, true);
    *(uint2*)(out8 + (size_t)i * 8) = make_uint2(a, b);
}

// ---------------- weight prep: WT_t = combined W^T in fragment-tiled layout ------------
__global__ __launch_bounds__(256) void build_wcomb(
    const float* __restrict__ Wl, const float* __restrict__ bl,
    const float* __restrict__ Wr, unsigned short* __restrict__ WTt, float* __restrict__ bc)
{
    int idx = blockIdx.x * 256 + threadIdx.x;
    if (idx < 2 * 2 * DD * KTOT) {
        int k  = idx % KTOT;
        int t1 = idx / KTOT;
        int i  = t1 & 127;
        int t2 = t1 >> 7;
        int dt = t2 & 1;      // 0 = dst d, 1 = dst m
        int l  = t2 >> 1;
        int ta = dt ? 1 : 0;  // d: dd(0), m: mm(1)
        int tb = dt ? 2 : 3;  // d: md(3), m: dm(2)
        float v;
        if (k < 128) {
            v = Wl[(((size_t)(l * 4 + ta) * 128 + i) << 7) + k];
        } else if (k < 256) {
            v = Wl[(((size_t)(l * 4 + tb) * 128 + i) << 7) + (k - 128)];
        } else {
            int kk = k - 256;
            v = Wr[(((size_t)(l * 4 + ta) * 128 + i) << 7) + kk]
              + Wr[(((size_t)(l * 4 + tb) * 128 + i) << 7) + kk];
        }
        int tidx = ((((i >> 4) * 12 + (k >> 5)) * 64) + (((k >> 3) & 3) * 16 + (i & 15))) * 8
                 + (k & 7);
        WTt[(size_t)t2 * (DD * KTOT) + tidx] = f2b(v);
    }
    if (idx < 512) {
        int i  = idx & 127;
        int t2 = idx >> 7;
        int dt = t2 & 1;
        int l  = t2 >> 1;
        int ta = dt ? 1 : 0;
        int tb = dt ? 2 : 3;
        bc[idx] = bl[(l * 4 + ta) * 128 + i] + bl[(l * 4 + tb) * 128 + i];
    }
}

// ---------------- phase A: LDS-binned edge staging, fixed-CAP bucket regions ----------
__global__ __launch_bounds__(512) void bin_edges(
    const void* __restrict__ e0, const void* __restrict__ e1,
    const void* __restrict__ e2, const void* __restrict__ e3,
    int E0, int E1, int E2, int E3,
    const int* __restrict__ flag, int* __restrict__ bucket_fill,
    unsigned* __restrict__ stage,
    unsigned long long* __restrict__ ovf, int* __restrict__ ovf_cnt,
    int N, int nb)
{
    __shared__ unsigned sb_pack[CHUNK];
    __shared__ unsigned short sb_b[CHUNK];
    __shared__ int hist[NBMAX];
    __shared__ int offs[NBMAX];
    __shared__ int base[NBMAX];

    const int tid   = threadIdx.x;
    const int E_tot = E0 + E1 + E2 + E3;
    const int e_bas = blockIdx.x * CHUNK;
    const int e_end = min(e_bas + CHUNK, E_tot);
    const int cnt_e = e_end - e_bas;
    const int isI32 = *flag;

    for (int i = tid; i < nb; i += 512) hist[i] = 0;
    __syncthreads();

    unsigned my_pack[4];
    int my_b[4], my_r[4];
    #pragma unroll
    for (int u = 0; u < 4; ++u) {
        my_b[u] = -1;
        int e = e_bas + tid + u * 512;
        if (e < e_end) {
            const void* ep; int El, type, le = e;
            if (le < E0)              { ep = e0; El = E0; type = 0; }
            else if ((le -= E0) < E1) { ep = e1; El = E1; type = 1; }
            else if ((le -= E1) < E2) { ep = e2; El = E2; type = 2; }
            else                      { le -= E2; ep = e3; El = E3; type = 3; }
            int s, d;
            if (isI32) {
                s = ((const int*)ep)[le];
                d = ((const int*)ep)[(size_t)El + le];
            } else {
                s = (int)((const long long*)ep)[le];
                d = (int)((const long long*)ep)[(size_t)El + le];
            }
            int gnode = type * N + d;
            int b = gnode >> BS_BITS;
            my_b[u]    = b;
            my_pack[u] = ((unsigned)s << BS_BITS) | (unsigned)(gnode & (BS - 1));
            my_r[u]    = atomicAdd(&hist[b], 1);
        }
    }
    __syncthreads();

    offs[tid] = (tid < nb) ? hist[tid] : 0;
    __syncthreads();
    for (int d = 1; d < 512; d <<= 1) {
        int v = (tid >= d) ? offs[tid - d] : 0;
        __syncthreads();
        offs[tid] += v;
        __syncthreads();
    }
    if (tid < nb) {
        offs[tid] -= hist[tid];                              // exclusive
        base[tid] = hist[tid] ? atomicAdd(&bucket_fill[tid], hist[tid]) : 0;
    }
    __syncthreads();

    #pragma unroll
    for (int u = 0; u < 4; ++u) {
        if (my_b[u] >= 0) {
            int pos = offs[my_b[u]] + my_r[u];
            sb_pack[pos] = my_pack[u];
            sb_b[pos]    = (unsigned short)my_b[u];
        }
    }
    __syncthreads();

    for (int pos = tid; pos < cnt_e; pos += 512) {
        int b = sb_b[pos];
        unsigned p = sb_pack[pos];
        int idx = base[b] + (pos - offs[b]);
        if (idx < CAP) {
            stage[(size_t)b * CAP + idx] = p;
        } else {                                             // overflow (expected: never)
            int k = atomicAdd(ovf_cnt, 1);
            int gnode = (b << BS_BITS) | (int)(p & (BS - 1));
            ovf[k] = ((unsigned long long)(unsigned)gnode << 32) | (p >> BS_BITS);
        }
    }
}

// ---------------- exclusive scan over bucket totals (1 block) ----------------
__global__ __launch_bounds__(512) void scan_buckets(const int* __restrict__ fill, int nb,
                                                    int* __restrict__ base)
{
    __shared__ int s[512];
    const int tid = threadIdx.x;
    int v = (tid < nb) ? fill[tid] : 0;
    s[tid] = v;
    __syncthreads();
    for (int d = 1; d < 512; d <<= 1) {
        int u = (tid >= d) ? s[tid - d] : 0;
        __syncthreads();
        s[tid] += u;
        __syncthreads();
    }
    if (tid < nb) base[tid] = s[tid] - v;    // exclusive
}

// ---------------- phase B: per-bucket count + scan + rp/inv + CSR fill ----------------
__global__ __launch_bounds__(512) void fill_from_stage(
    const unsigned* __restrict__ stage, const int* __restrict__ bucket_fill,
    const int* __restrict__ bucket_base,
    const unsigned long long* __restrict__ ovf, const int* __restrict__ ovf_cnt,
    int* __restrict__ rp_all, float* __restrict__ inv_all, int* __restrict__ col, int n4)
{
    __shared__ int cl[BS];     // counts, later cursors
    __shared__ int rl[BS];     // exclusive scan
    __shared__ int w[512];

    const int tid   = threadIdx.x;
    const int b     = blockIdx.x;
    const int node0 = b << BS_BITS;
    const int nn    = min(BS, n4 - node0);

    cl[tid] = 0; cl[tid + 512] = 0;
    __syncthreads();

    const int total  = bucket_fill[b];
    const int nstage = min(total, CAP);
    const unsigned* st = stage + (size_t)b * CAP;
    const int novf = *ovf_cnt;

    for (int j = tid; j < nstage; j += 512)
        atomicAdd(&cl[st[j] & (BS - 1)], 1);
    for (int k = tid; k < novf; k += 512) {
        int g = (int)(ovf[k] >> 32);
        if (g >= node0 && g < node0 + nn) atomicAdd(&cl[g - node0], 1);
    }
    __syncthreads();

    int a0 = cl[2 * tid], a1 = cl[2 * tid + 1];
    w[tid] = a0 + a1;
    __syncthreads();
    for (int d = 1; d < 512; d <<= 1) {
        int v = (tid >= d) ? w[tid - d] : 0;
        __syncthreads();
        w[tid] += v;
        __syncthreads();
    }
    int excl = w[tid] - a0 - a1;
    rl[2 * tid]     = excl;
    rl[2 * tid + 1] = excl + a0;
    __syncthreads();

    const int gbase = bucket_base[b];
    for (int i = tid; i < nn; i += 512) {
        rp_all[node0 + i] = gbase + rl[i];
        inv_all[node0 + i] = 1.0f / (float)max(cl[i], 1);
    }
    if (b == gridDim.x - 1 && tid == 0) rp_all[n4] = gbase + total;
    __syncthreads();

    for (int i = tid; i < BS; i += 512) cl[i] = gbase + rl[i];
    __syncthreads();

    for (int j = tid; j < nstage; j += 512) {
        unsigned p = st[j];
        int slot = atomicAdd(&cl[p & (BS - 1)], 1);
        col[slot] = (int)(p >> BS_BITS);
    }
    for (int k = tid; k < novf; k += 512) {
        unsigned long long p = ovf[k];
        int g = (int)(p >> 32);
        if (g >= node0 && g < node0 + nn) {
            int slot = atomicAdd(&cl[g - node0], 1);
            col[slot] = (int)(p & 0xffffffffu);
        }
    }
}

// ---------------- gather-aggregate BOTH dst types into fragment-tiled A_t ----------------
// MIXED precision: segA (tree, deg~1, no error averaging) gathers bf16 x;
//                  segB (link, deg~10, mean smooths fp8 noise) gathers fp8 x8.
__global__ __launch_bounds__(256) void aggregate_all(
    const unsigned short* __restrict__ x, const unsigned char* __restrict__ x8,
    const int* __restrict__ rp, const float* __restrict__ inv,
    const int* __restrict__ col, unsigned short* __restrict__ At, int N)
{
    long long g = (long long)blockIdx.x * 256 + threadIdx.x;
    int node = (int)(g >> 4);
    int q    = (int)(g & 15);          // lane: 8 elems (16 B bf16 / 8 B fp8)
    if (node >= 2 * N) return;

    const int isM  = node >= N;
    const int segA = node + (isM ? N : 0);
    const int segB = segA + N;
    const int selfbase  = isM ? N : 0;
    const int otherbase = N - selfbase;

    const int r16 = node >> 4;
    const int fr  = node & 15;
    unsigned short* tbase = At + ((size_t)r16 * 8 + (q >> 2)) * 512 + ((q & 3) * 16 + fr) * 8;

    const unsigned short* xs = x  + (size_t)selfbase  * DD + q * 8;   // bf16 self
    const unsigned char*  xo = x8 + (size_t)otherbase * DD + q * 8;   // fp8 other

    float aL[4], aH[4], accB[8];
    #pragma unroll
    for (int t = 0; t < 4; ++t) { aL[t]=0.f; aH[t]=0.f; }
    #pragma unroll
    for (int t = 0; t < 8; ++t) accB[t] = 0.f;

    int jA = rp[segA], eA = rp[segA + 1];
    int jB = rp[segB], eB = rp[segB + 1];

    // ---- segB: fp8, 8-deep independent loads ----
    while (jB + 8 <= eB) {
        int b0 = col[jB],   b1 = col[jB+1], b2 = col[jB+2], b3 = col[jB+3];
        int b4 = col[jB+4], b5 = col[jB+5], b6 = col[jB+6], b7 = col[jB+7];
        uint2 v0 = *(const uint2*)(xo + (size_t)b0 * DD);
        uint2 v1 = *(const uint2*)(xo + (size_t)b1 * DD);
        uint2 v2 = *(const uint2*)(xo + (size_t)b2 * DD);
        uint2 v3 = *(const uint2*)(xo + (size_t)b3 * DD);
        uint2 v4 = *(const uint2*)(xo + (size_t)b4 * DD);
        uint2 v5 = *(const uint2*)(xo + (size_t)b5 * DD);
        uint2 v6 = *(const uint2*)(xo + (size_t)b6 * DD);
        uint2 v7 = *(const uint2*)(xo + (size_t)b7 * DD);
        ACC_F8(accB, v0.x, v0.y); ACC_F8(accB, v1.x, v1.y);
        ACC_F8(accB, v2.x, v2.y); ACC_F8(accB, v3.x, v3.y);
        ACC_F8(accB, v4.x, v4.y); ACC_F8(accB, v5.x, v5.y);
        ACC_F8(accB, v6.x, v6.y); ACC_F8(accB, v7.x, v7.y);
        jB += 8;
    }
    while (jB + 4 <= eB) {
        int b0 = col[jB], b1 = col[jB+1], b2 = col[jB+2], b3 = col[jB+3];
        uint2 v0 = *(const uint2*)(xo + (size_t)b0 * DD);
        uint2 v1 = *(const uint2*)(xo + (size_t)b1 * DD);
        uint2 v2 = *(const uint2*)(xo + (size_t)b2 * DD);
        uint2 v3 = *(const uint2*)(xo + (size_t)b3 * DD);
        ACC_F8(accB, v0.x, v0.y); ACC_F8(accB, v1.x, v1.y);
        ACC_F8(accB, v2.x, v2.y); ACC_F8(accB, v3.x, v3.y);
        jB += 4;
    }
    if (jB + 2 <= eB) {
        int b0 = col[jB], b1 = col[jB+1];
        uint2 v0 = *(const uint2*)(xo + (size_t)b0 * DD);
        uint2 v1 = *(const uint2*)(xo + (size_t)b1 * DD);
        ACC_F8(accB, v0.x, v0.y); ACC_F8(accB, v1.x, v1.y);
        jB += 2;
    }
    if (jB < eB) {
        uint2 v = *(const uint2*)(xo + (size_t)col[jB] * DD);
        ACC_F8(accB, v.x, v.y);
    }

    // ---- segA: bf16, tree edges (short lists) ----
    while (jA + 2 <= eA) {
        int a0 = col[jA], a1 = col[jA+1];
        uint4 v0 = *(const uint4*)(xs + (size_t)a0 * DD);
        uint4 v1 = *(const uint4*)(xs + (size_t)a1 * DD);
        ACC_PAIR(aL[0], aH[0], v0.x); ACC_PAIR(aL[1], aH[1], v0.y);
        ACC_PAIR(aL[2], aH[2], v0.z); ACC_PAIR(aL[3], aH[3], v0.w);
        ACC_PAIR(aL[0], aH[0], v1.x); ACC_PAIR(aL[1], aH[1], v1.y);
        ACC_PAIR(aL[2], aH[2], v1.z); ACC_PAIR(aL[3], aH[3], v1.w);
        jA += 2;
    }
    if (jA < eA) {
        uint4 v = *(const uint4*)(xs + (size_t)col[jA] * DD);
        ACC_PAIR(aL[0], aH[0], v.x); ACC_PAIR(aL[1], aH[1], v.y);
        ACC_PAIR(aL[2], aH[2], v.z); ACC_PAIR(aL[3], aH[3], v.w);
    }

    float scA = inv[segA], scB = inv[segB];
    ushort8 rA, rB;
    #pragma unroll
    for (int t = 0; t < 4; ++t) {
        rA[2*t]   = f2b(aL[t] * scA);
        rA[2*t+1] = f2b(aH[t] * scA);
    }
    #pragma unroll
    for (int t = 0; t < 8; ++t) rB[t] = f2b(accB[t] * scB);
    *(ushort8*)(tbase)           = rA;
    *(ushort8*)(tbase + 4 * 512) = rB;
}

// ---------------- MFMA GEMM, LDS-free, swapped operands, FULL A-preload ----------------
// BM=64, 2 r16 tiles/wave. All 12 A k-fragments per tile preloaded upfront:
// 24 independent loads in flight; L3 latency paid once per wave, not per k-step.
// mfma(W_frag, A_frag): lane holds 4 consecutive FEATURES of one node -> vector stores.
__global__ __launch_bounds__(256) void gemm_mfma(
    const unsigned short* __restrict__ At, const unsigned short* __restrict__ x,
    const unsigned short* __restrict__ WTt, const float* __restrict__ bc,
    void* __restrict__ outp, unsigned char* __restrict__ out8,
    int relu, int write_f32, int N, int gd)
{
    const int tid = threadIdx.x;
    const int b   = blockIdx.x;
    const int isM = (b >= gd);
    const int row0   = isM ? N + (b - gd) * BM : b * BM;
    const int rowlim = isM ? 2 * N : N;
    const int tlim   = (rowlim >> 4) - 1;

    const float* bias = bc + isM * DD;

    const int wave = tid >> 6;
    const int lane = tid & 63;
    const int wc = (wave & 1) * 64;          // 0 / 64 (feature half)
    const int fr  = lane & 15;
    const int fk8 = lane >> 4;

    int r16a = (row0 >> 4) + (wave >> 1) * 2;
    int r16b = r16a + 1;
    if (r16a > tlim) r16a = tlim;
    if (r16b > tlim) r16b = tlim;

    const unsigned short* Abase0 = At + (size_t)r16a * 8 * 512 + lane * 8;
    const unsigned short* Abase1 = At + (size_t)r16b * 8 * 512 + lane * 8;
    const unsigned short* Xbase0 = x + (size_t)(r16a * 16 + fr) * DD + fk8 * 8;
    const unsigned short* Xbase1 = x + (size_t)(r16b * 16 + fr) * DD + fk8 * 8;
    const unsigned short* Wbase  = WTt + (size_t)isM * DD * KTOT + (size_t)(wc >> 4) * 12 * 512 + lane * 8;

    // ---- preload ALL A fragments: 24 independent loads issued back-to-back ----
    short8 aF0[12], aF1[12];
    #pragma unroll
    for (int k = 0; k < 8; ++k) {
        aF0[k] = *(const short8*)(Abase0 + k * 512);
        aF1[k] = *(const short8*)(Abase1 + k * 512);
    }
    #pragma unroll
    for (int k = 8; k < 12; ++k) {
        aF0[k] = *(const short8*)(Xbase0 + (k - 8) * 32);
        aF1[k] = *(const short8*)(Xbase1 + (k - 8) * 32);
    }

    floatx4 acc[2][4] = {};

    short8 bC[4], bN[4];
    #pragma unroll
    for (int c = 0; c < 4; ++c) bC[c] = *(const short8*)(Wbase + (size_t)c * 12 * 512);

    #pragma unroll
    for (int ks = 0; ks < 12; ++ks) {
        if (ks + 1 < 12) {
            #pragma unroll
            for (int c = 0; c < 4; ++c)
                bN[c] = *(const short8*)(Wbase + (size_t)c * 12 * 512 + (ks + 1) * 512);
        }
        // swapped operands: W as A-operand (rows=features), nodes as B-operand (cols)
        #pragma unroll
        for (int c = 0; c < 4; ++c) {
            acc[0][c] = __builtin_amdgcn_mfma_f32_16x16x32_bf16(bC[c], aF0[ks], acc[0][c], 0, 0, 0);
            acc[1][c] = __builtin_amdgcn_mfma_f32_16x16x32_bf16(bC[c], aF1[ks], acc[1][c], 0, 0, 0);
        }
        #pragma unroll
        for (int c = 0; c < 4; ++c) bC[c] = bN[c];
    }

    // epilogue: node = r16*16 + fr (col), feats = wc + c*16 + fk8*4 + i (rows) — vector stores
    float* outf = (float*)outp;
    unsigned short* outb = (unsigned short*)outp;
    const int rb = fk8 * 4;
    const int nodes[2] = { r16a * 16 + fr, r16b * 16 + fr };
    #pragma unroll
    for (int m = 0; m < 2; ++m) {
        size_t rowoff = (size_t)nodes[m] * DD;
        #pragma unroll
        for (int c = 0; c < 4; ++c) {
            int f0 = wc + c * 16 + rb;
            float4 bb = *(const float4*)(bias + f0);
            float v0 = acc[m][c][0] + bb.x;
            float v1 = acc[m][c][1] + bb.y;
            float v2 = acc[m][c][2] + bb.z;
            float v3 = acc[m][c][3] + bb.w;
            if (relu) {
                v0 = fmaxf(v0, 0.f); v1 = fmaxf(v1, 0.f);
                v2 = fmaxf(v2, 0.f); v3 = fmaxf(v3, 0.f);
            }
            if (write_f32) {
                *(float4*)(outf + rowoff + f0) = make_float4(v0, v1, v2, v3);
            } else {
                ushort4 h;
                h.x = f2b(v0); h.y = f2b(v1); h.z = f2b(v2); h.w = f2b(v3);
                *(ushort4*)(outb + rowoff + f0) = h;
                unsigned e = 0;
                e = __builtin_amdgcn_cvt_pk_fp8_f32(v0, v1, e, false);
                e = __builtin_amdgcn_cvt_pk_fp8_f32(v2, v3, e, true);
                *(unsigned*)(out8 + rowoff + f0) = e;
            }
        }
    }
}

extern "C" void kernel_launch(void* const* d_in, const int* in_sizes, int n_in,
                              void* d_out, int out_size, void* d_ws, size_t ws_size,
                              hipStream_t stream)
{
    const float* x_d = (const float*)d_in[0];
    const float* x_m = (const float*)d_in[1];
    const float* Wl  = (const float*)d_in[6];
    const float* bl  = (const float*)d_in[7];
    const float* Wr  = (const float*)d_in[8];
    float* out = (float*)d_out;

    const int N    = in_sizes[0] / DD;
    const int E_dd = in_sizes[2] / 2;
    const int E_mm = in_sizes[3] / 2;
    const int E_dm = in_sizes[4] / 2;
    const int E_md = in_sizes[5] / 2;
    const int E_tot = E_dd + E_md + E_mm + E_dm;
    const int n4 = 4 * N;
    const int nb = (n4 + BS - 1) >> BS_BITS;
    const int M16 = (2 * N + 15) >> 4;

    char* ws = (char*)d_ws;
    size_t off = 0;
    auto alloc = [&](size_t bytes) {
        void* p = ws + off;
        off += (bytes + 255) & ~(size_t)255;
        return p;
    };
    unsigned short* xb   = (unsigned short*)alloc((size_t)2 * N * DD * 2);  // [xd|xm] bf16
    unsigned short* hb   = (unsigned short*)alloc((size_t)2 * N * DD * 2);  // [hd|hm] bf16
    unsigned char*  x8   = (unsigned char*) alloc((size_t)2 * N * DD);      // fp8 mirror of x
    unsigned char*  h8   = (unsigned char*) alloc((size_t)2 * N * DD);      // fp8 mirror of h
    unsigned short* At   = (unsigned short*)alloc((size_t)M16 * 8 * 512 * 2);
    float* inv_all = (float*)alloc((size_t)n4 * 4);
    int*   rp_all  = (int*)  alloc((size_t)(n4 + 1) * 4);
    int*   bucket_fill = (int*)alloc((size_t)NBMAX * 4);
    int*   bucket_base = (int*)alloc((size_t)NBMAX * 4);
    unsigned short* WTt = (unsigned short*)alloc((size_t)2 * 2 * DD * KTOT * 2);
    float* bc      = (float*)alloc((size_t)512 * 4);
    unsigned* stage = (unsigned*)alloc((size_t)nb * CAP * 4);
    int*   col     = (int*)alloc((size_t)E_tot * 4);
    unsigned long long* ovf = (unsigned long long*)alloc((size_t)(1 << 18) * 8);
    int*   ovf_cnt = (int*)alloc(256);
    int*   flag    = (int*)alloc(256);

    // ---- edge dtype probe ----
    hipMemsetAsync(flag, 0, 256, stream);
    detect_i32<<<4, 256, 0, stream>>>((const int*)d_in[2], 1024, flag);

    // ---- x -> bf16 + fp8 mirror ([xd|xm] contiguous) ----
    const int n8 = N * DD / 8;
    cvt_bf16<<<(n8 + 255) / 256, 256, 0, stream>>>(x_d, xb, x8, n8);
    cvt_bf16<<<(n8 + 255) / 256, 256, 0, stream>>>(x_m, xb + (size_t)N * DD,
                                                   x8 + (size_t)N * DD, n8);

    // ---- CSR build: bin -> bucket scan -> per-bucket count/scan/fill ----
    hipMemsetAsync(bucket_fill, 0, (size_t)NBMAX * 4, stream);
    hipMemsetAsync(ovf_cnt, 0, 256, stream);
    const int nchunks = (E_tot + CHUNK - 1) / CHUNK;
    bin_edges<<<nchunks, 512, 0, stream>>>(
        d_in[2], d_in[5], d_in[3], d_in[4], E_dd, E_md, E_mm, E_dm,
        flag, bucket_fill, stage, ovf, ovf_cnt, N, nb);
    scan_buckets<<<1, 512, 0, stream>>>(bucket_fill, nb, bucket_base);
    fill_from_stage<<<nb, 512, 0, stream>>>(
        stage, bucket_fill, bucket_base, ovf, ovf_cnt, rp_all, inv_all, col, n4);

    build_wcomb<<<(2 * 2 * DD * KTOT + 255) / 256, 256, 0, stream>>>(Wl, bl, Wr, WTt, bc);

    const int agg_grid = (int)(((size_t)2 * N * 16 + 255) / 256);
    const int gd = (N + BM - 1) / BM;
    const int gemm_grid = 2 * gd;
    const unsigned short* xcur = xb;
    const unsigned char*  xcur8 = x8;
    for (int l = 0; l < 2; ++l) {
        int relu = (l == 0);
        int wf32 = (l == 1);
        void* ob = (l == 1) ? (void*)out : (void*)hb;

        aggregate_all<<<agg_grid, 256, 0, stream>>>(xcur, xcur8, rp_all, inv_all, col, At, N);
        gemm_mfma<<<gemm_grid, 256, 0, stream>>>(
            At, xcur, WTt + (size_t)l * 2 * DD * KTOT, bc + l * 2 * DD,
            ob, h8, relu, wf32, N, gd);

        xcur = hb;
        xcur8 = h8;
    }
}

// Round 23
// 362.875 us; speedup vs baseline: 1.0873x; 1.0271x over previous
//
#include <hip/hip_runtime.h>

#define DD 128
#define KTOT 384
#define BM 64
#define BS_BITS 10
#define BS 1024          // nodes per bucket
#define NBMAX 512        // max buckets (4N <= 512K)
#define CHUNK 4096       // edges per bin_edges block (R23: 2048->4096)
#define CAP 12288        // stage slots per bucket (max expected ~10.6K)

typedef __attribute__((ext_vector_type(8))) short short8;
typedef __attribute__((ext_vector_type(8))) unsigned short ushort8;
typedef __attribute__((ext_vector_type(4))) float floatx4;
typedef __attribute__((ext_vector_type(2))) float floatx2;

__device__ __forceinline__ unsigned short f2b(float f) {
    union { float f; unsigned u; } v; v.f = f;
    return (unsigned short)((v.u + 0x7fffu + ((v.u >> 16) & 1u)) >> 16);
}
__device__ __forceinline__ float b2f(unsigned short u) {
    union { unsigned u; float f; } v; v.u = ((unsigned)u) << 16;
    return v.f;
}
__device__ __forceinline__ float asf(unsigned u) {
    union { unsigned u; float f; } v; v.u = u; return v.f;
}

// bf16 pair-accumulate: u32 = (bf16_hi<<16)|bf16_lo (R16-verified)
#define ACC_PAIR(accL, accH, u) { accH += asf(u); accL += asf((u) << 16); }

// decode 8 fp8 (e4m3) from uint2 and accumulate into acc[8] — HW packed cvt
#define ACC_F8(acc, ux, uy) { \
    floatx2 p0 = __builtin_amdgcn_cvt_pk_f32_fp8((ux), false); \
    floatx2 p1 = __builtin_amdgcn_cvt_pk_f32_fp8((ux), true);  \
    floatx2 p2 = __builtin_amdgcn_cvt_pk_f32_fp8((uy), false); \
    floatx2 p3 = __builtin_amdgcn_cvt_pk_f32_fp8((uy), true);  \
    acc[0] += p0.x; acc[1] += p0.y; acc[2] += p1.x; acc[3] += p1.y; \
    acc[4] += p2.x; acc[5] += p2.y; acc[6] += p3.x; acc[7] += p3.y; }

// ---------------- edge dtype probe: int64 arrays have all-zero odd int32 words ----------
__global__ __launch_bounds__(256) void detect_i32(const int* __restrict__ p, int nodd,
                                                  int* __restrict__ flag)
{
    int i = blockIdx.x * 256 + threadIdx.x;
    if (i < nodd && p[2 * i + 1] != 0) atomicOr(flag, 1);
}

// ---------------- x -> bf16 (row-major) + fp8 gather mirror; both node types fused ------
__global__ __launch_bounds__(256) void cvt_bf16(const float* __restrict__ in_d,
                                                const float* __restrict__ in_m,
                                                unsigned short* __restrict__ out,
                                                unsigned char* __restrict__ out8,
                                                int n8half, int n8)
{
    int i = blockIdx.x * 256 + threadIdx.x;
    if (i >= n8) return;
    const float* in = (i < n8half) ? in_d : (in_m - (size_t)n8half * 8);
    float4 v0 = *(const float4*)(in + (size_t)i * 8);
    float4 v1 = *(const float4*)(in + (size_t)i * 8 + 4);
    ushort8 r;
    r[0]=f2b(v0.x); r[1]=f2b(v0.y); r[2]=f2b(v0.z); r[3]=f2b(v0.w);
    r[4]=f2b(v1.x); r[5]=f2b(v1.y); r[6]=f2b(v1.z); r[7]=f2b(v1.w);
    *(ushort8*)(out + (size_t)i * 8) = r;
    unsigned a = 0, b = 0;
    a = __builtin_amdgcn_cvt_pk_fp8_f32(v0.x, v0.y, a, false);
    a = __builtin_amdgcn_cvt_pk_fp8_f32(v0.z, v0.w, a, true);
    b = __builtin_amdgcn_cvt_pk_fp8_f32(v1.x, v1.y, b, false);
    b = __builtin_amdgcn_cvt_pk_fp8_f32(v1.z, v1.w, b, true);
    *(uint2*)(out8 + (size_t)i * 8) = make_uint2(a, b);
}

// ---------------- weight prep: WT_t = combined W^T in fragment-tiled layout ------------
__global__ __launch_bounds__(256) void build_wcomb(
    const float* __restrict__ Wl, const float* __restrict__ bl,
    const float* __restrict__ Wr, unsigned short* __restrict__ WTt, float* __restrict__ bc)
{
    int idx = blockIdx.x * 256 + threadIdx.x;
    if (idx < 2 * 2 * DD * KTOT) {
        int k  = idx % KTOT;
        int t1 = idx / KTOT;
        int i  = t1 & 127;
        int t2 = t1 >> 7;
        int dt = t2 & 1;      // 0 = dst d, 1 = dst m
        int l  = t2 >> 1;
        int ta = dt ? 1 : 0;  // d: dd(0), m: mm(1)
        int tb = dt ? 2 : 3;  // d: md(3), m: dm(2)
        float v;
        if (k < 128) {
            v = Wl[(((size_t)(l * 4 + ta) * 128 + i) << 7) + k];
        } else if (k < 256) {
            v = Wl[(((size_t)(l * 4 + tb) * 128 + i) << 7) + (k - 128)];
        } else {
            int kk = k - 256;
            v = Wr[(((size_t)(l * 4 + ta) * 128 + i) << 7) + kk]
              + Wr[(((size_t)(l * 4 + tb) * 128 + i) << 7) + kk];
        }
        int tidx = ((((i >> 4) * 12 + (k >> 5)) * 64) + (((k >> 3) & 3) * 16 + (i & 15))) * 8
                 + (k & 7);
        WTt[(size_t)t2 * (DD * KTOT) + tidx] = f2b(v);
    }
    if (idx < 512) {
        int i  = idx & 127;
        int t2 = idx >> 7;
        int dt = t2 & 1;
        int l  = t2 >> 1;
        int ta = dt ? 1 : 0;
        int tb = dt ? 2 : 3;
        bc[idx] = bl[(l * 4 + ta) * 128 + i] + bl[(l * 4 + tb) * 128 + i];
    }
}

// ---------------- phase A: LDS-binned edge staging, fixed-CAP bucket regions ----------
__global__ __launch_bounds__(512) void bin_edges(
    const void* __restrict__ e0, const void* __restrict__ e1,
    const void* __restrict__ e2, const void* __restrict__ e3,
    int E0, int E1, int E2, int E3,
    const int* __restrict__ flag, int* __restrict__ bucket_fill,
    unsigned* __restrict__ stage,
    unsigned long long* __restrict__ ovf, int* __restrict__ ovf_cnt,
    int N, int nb)
{
    __shared__ unsigned sb_pack[CHUNK];
    __shared__ unsigned short sb_b[CHUNK];
    __shared__ int hist[NBMAX];
    __shared__ int offs[NBMAX];
    __shared__ int base[NBMAX];

    const int tid   = threadIdx.x;
    const int E_tot = E0 + E1 + E2 + E3;
    const int e_bas = blockIdx.x * CHUNK;
    const int e_end = min(e_bas + CHUNK, E_tot);
    const int cnt_e = e_end - e_bas;
    const int isI32 = *flag;

    for (int i = tid; i < nb; i += 512) hist[i] = 0;
    __syncthreads();

    unsigned my_pack[8];
    int my_b[8], my_r[8];
    #pragma unroll
    for (int u = 0; u < 8; ++u) {
        my_b[u] = -1;
        int e = e_bas + tid + u * 512;
        if (e < e_end) {
            const void* ep; int El, type, le = e;
            if (le < E0)              { ep = e0; El = E0; type = 0; }
            else if ((le -= E0) < E1) { ep = e1; El = E1; type = 1; }
            else if ((le -= E1) < E2) { ep = e2; El = E2; type = 2; }
            else                      { le -= E2; ep = e3; El = E3; type = 3; }
            int s, d;
            if (isI32) {
                s = ((const int*)ep)[le];
                d = ((const int*)ep)[(size_t)El + le];
            } else {
                s = (int)((const long long*)ep)[le];
                d = (int)((const long long*)ep)[(size_t)El + le];
            }
            int gnode = type * N + d;
            int b = gnode >> BS_BITS;
            my_b[u]    = b;
            my_pack[u] = ((unsigned)s << BS_BITS) | (unsigned)(gnode & (BS - 1));
            my_r[u]    = atomicAdd(&hist[b], 1);
        }
    }
    __syncthreads();

    offs[tid] = (tid < nb) ? hist[tid] : 0;
    __syncthreads();
    for (int d = 1; d < 512; d <<= 1) {
        int v = (tid >= d) ? offs[tid - d] : 0;
        __syncthreads();
        offs[tid] += v;
        __syncthreads();
    }
    if (tid < nb) {
        offs[tid] -= hist[tid];                              // exclusive
        base[tid] = hist[tid] ? atomicAdd(&bucket_fill[tid], hist[tid]) : 0;
    }
    __syncthreads();

    #pragma unroll
    for (int u = 0; u < 8; ++u) {
        if (my_b[u] >= 0) {
            int pos = offs[my_b[u]] + my_r[u];
            sb_pack[pos] = my_pack[u];
            sb_b[pos]    = (unsigned short)my_b[u];
        }
    }
    __syncthreads();

    for (int pos = tid; pos < cnt_e; pos += 512) {
        int b = sb_b[pos];
        unsigned p = sb_pack[pos];
        int idx = base[b] + (pos - offs[b]);
        if (idx < CAP) {
            stage[(size_t)b * CAP + idx] = p;
        } else {                                             // overflow (expected: never)
            int k = atomicAdd(ovf_cnt, 1);
            int gnode = (b << BS_BITS) | (int)(p & (BS - 1));
            ovf[k] = ((unsigned long long)(unsigned)gnode << 32) | (p >> BS_BITS);
        }
    }
}

// ---------------- exclusive scan over bucket totals (1 block) ----------------
__global__ __launch_bounds__(512) void scan_buckets(const int* __restrict__ fill, int nb,
                                                    int* __restrict__ base)
{
    __shared__ int s[512];
    const int tid = threadIdx.x;
    int v = (tid < nb) ? fill[tid] : 0;
    s[tid] = v;
    __syncthreads();
    for (int d = 1; d < 512; d <<= 1) {
        int u = (tid >= d) ? s[tid - d] : 0;
        __syncthreads();
        s[tid] += u;
        __syncthreads();
    }
    if (tid < nb) base[tid] = s[tid] - v;    // exclusive
}

// ---------------- phase B: per-bucket count + scan + rp/inv + CSR fill ----------------
__global__ __launch_bounds__(512) void fill_from_stage(
    const unsigned* __restrict__ stage, const int* __restrict__ bucket_fill,
    const int* __restrict__ bucket_base,
    const unsigned long long* __restrict__ ovf, const int* __restrict__ ovf_cnt,
    int* __restrict__ rp_all, float* __restrict__ inv_all, int* __restrict__ col, int n4)
{
    __shared__ int cl[BS];     // counts, later cursors
    __shared__ int rl[BS];     // exclusive scan
    __shared__ int w[512];

    const int tid   = threadIdx.x;
    const int b     = blockIdx.x;
    const int node0 = b << BS_BITS;
    const int nn    = min(BS, n4 - node0);

    cl[tid] = 0; cl[tid + 512] = 0;
    __syncthreads();

    const int total  = bucket_fill[b];
    const int nstage = min(total, CAP);
    const unsigned* st = stage + (size_t)b * CAP;
    const int novf = *ovf_cnt;

    for (int j = tid; j < nstage; j += 512)
        atomicAdd(&cl[st[j] & (BS - 1)], 1);
    for (int k = tid; k < novf; k += 512) {
        int g = (int)(ovf[k] >> 32);
        if (g >= node0 && g < node0 + nn) atomicAdd(&cl[g - node0], 1);
    }
    __syncthreads();

    int a0 = cl[2 * tid], a1 = cl[2 * tid + 1];
    w[tid] = a0 + a1;
    __syncthreads();
    for (int d = 1; d < 512; d <<= 1) {
        int v = (tid >= d) ? w[tid - d] : 0;
        __syncthreads();
        w[tid] += v;
        __syncthreads();
    }
    int excl = w[tid] - a0 - a1;
    rl[2 * tid]     = excl;
    rl[2 * tid + 1] = excl + a0;
    __syncthreads();

    const int gbase = bucket_base[b];
    for (int i = tid; i < nn; i += 512) {
        rp_all[node0 + i] = gbase + rl[i];
        inv_all[node0 + i] = 1.0f / (float)max(cl[i], 1);
    }
    if (b == gridDim.x - 1 && tid == 0) rp_all[n4] = gbase + total;
    __syncthreads();

    for (int i = tid; i < BS; i += 512) cl[i] = gbase + rl[i];
    __syncthreads();

    for (int j = tid; j < nstage; j += 512) {
        unsigned p = st[j];
        int slot = atomicAdd(&cl[p & (BS - 1)], 1);
        col[slot] = (int)(p >> BS_BITS);
    }
    for (int k = tid; k < novf; k += 512) {
        unsigned long long p = ovf[k];
        int g = (int)(p >> 32);
        if (g >= node0 && g < node0 + nn) {
            int slot = atomicAdd(&cl[g - node0], 1);
            col[slot] = (int)(p & 0xffffffffu);
        }
    }
}

// ---------------- gather-aggregate BOTH dst types into fragment-tiled A_t ----------------
// MIXED precision: segA (tree, deg~1, no error averaging) gathers bf16 x;
//                  segB (link, deg~10, mean smooths fp8 noise) gathers fp8 x8.
__global__ __launch_bounds__(256) void aggregate_all(
    const unsigned short* __restrict__ x, const unsigned char* __restrict__ x8,
    const int* __restrict__ rp, const float* __restrict__ inv,
    const int* __restrict__ col, unsigned short* __restrict__ At, int N)
{
    long long g = (long long)blockIdx.x * 256 + threadIdx.x;
    int node = (int)(g >> 4);
    int q    = (int)(g & 15);          // lane: 8 elems (16 B bf16 / 8 B fp8)
    if (node >= 2 * N) return;

    const int isM  = node >= N;
    const int segA = node + (isM ? N : 0);
    const int segB = segA + N;
    const int selfbase  = isM ? N : 0;
    const int otherbase = N - selfbase;

    const int r16 = node >> 4;
    const int fr  = node & 15;
    unsigned short* tbase = At + ((size_t)r16 * 8 + (q >> 2)) * 512 + ((q & 3) * 16 + fr) * 8;

    const unsigned short* xs = x  + (size_t)selfbase  * DD + q * 8;   // bf16 self
    const unsigned char*  xo = x8 + (size_t)otherbase * DD + q * 8;   // fp8 other

    float aL[4], aH[4], accB[8];
    #pragma unroll
    for (int t = 0; t < 4; ++t) { aL[t]=0.f; aH[t]=0.f; }
    #pragma unroll
    for (int t = 0; t < 8; ++t) accB[t] = 0.f;

    int jA = rp[segA], eA = rp[segA + 1];
    int jB = rp[segB], eB = rp[segB + 1];

    // ---- segB: fp8, 8-deep independent loads ----
    while (jB + 8 <= eB) {
        int b0 = col[jB],   b1 = col[jB+1], b2 = col[jB+2], b3 = col[jB+3];
        int b4 = col[jB+4], b5 = col[jB+5], b6 = col[jB+6], b7 = col[jB+7];
        uint2 v0 = *(const uint2*)(xo + (size_t)b0 * DD);
        uint2 v1 = *(const uint2*)(xo + (size_t)b1 * DD);
        uint2 v2 = *(const uint2*)(xo + (size_t)b2 * DD);
        uint2 v3 = *(const uint2*)(xo + (size_t)b3 * DD);
        uint2 v4 = *(const uint2*)(xo + (size_t)b4 * DD);
        uint2 v5 = *(const uint2*)(xo + (size_t)b5 * DD);
        uint2 v6 = *(const uint2*)(xo + (size_t)b6 * DD);
        uint2 v7 = *(const uint2*)(xo + (size_t)b7 * DD);
        ACC_F8(accB, v0.x, v0.y); ACC_F8(accB, v1.x, v1.y);
        ACC_F8(accB, v2.x, v2.y); ACC_F8(accB, v3.x, v3.y);
        ACC_F8(accB, v4.x, v4.y); ACC_F8(accB, v5.x, v5.y);
        ACC_F8(accB, v6.x, v6.y); ACC_F8(accB, v7.x, v7.y);
        jB += 8;
    }
    while (jB + 4 <= eB) {
        int b0 = col[jB], b1 = col[jB+1], b2 = col[jB+2], b3 = col[jB+3];
        uint2 v0 = *(const uint2*)(xo + (size_t)b0 * DD);
        uint2 v1 = *(const uint2*)(xo + (size_t)b1 * DD);
        uint2 v2 = *(const uint2*)(xo + (size_t)b2 * DD);
        uint2 v3 = *(const uint2*)(xo + (size_t)b3 * DD);
        ACC_F8(accB, v0.x, v0.y); ACC_F8(accB, v1.x, v1.y);
        ACC_F8(accB, v2.x, v2.y); ACC_F8(accB, v3.x, v3.y);
        jB += 4;
    }
    if (jB + 2 <= eB) {
        int b0 = col[jB], b1 = col[jB+1];
        uint2 v0 = *(const uint2*)(xo + (size_t)b0 * DD);
        uint2 v1 = *(const uint2*)(xo + (size_t)b1 * DD);
        ACC_F8(accB, v0.x, v0.y); ACC_F8(accB, v1.x, v1.y);
        jB += 2;
    }
    if (jB < eB) {
        uint2 v = *(const uint2*)(xo + (size_t)col[jB] * DD);
        ACC_F8(accB, v.x, v.y);
    }

    // ---- segA: bf16, tree edges (short lists) ----
    while (jA + 2 <= eA) {
        int a0 = col[jA], a1 = col[jA+1];
        uint4 v0 = *(const uint4*)(xs + (size_t)a0 * DD);
        uint4 v1 = *(const uint4*)(xs + (size_t)a1 * DD);
        ACC_PAIR(aL[0], aH[0], v0.x); ACC_PAIR(aL[1], aH[1], v0.y);
        ACC_PAIR(aL[2], aH[2], v0.z); ACC_PAIR(aL[3], aH[3], v0.w);
        ACC_PAIR(aL[0], aH[0], v1.x); ACC_PAIR(aL[1], aH[1], v1.y);
        ACC_PAIR(aL[2], aH[2], v1.z); ACC_PAIR(aL[3], aH[3], v1.w);
        jA += 2;
    }
    if (jA < eA) {
        uint4 v = *(const uint4*)(xs + (size_t)col[jA] * DD);
        ACC_PAIR(aL[0], aH[0], v.x); ACC_PAIR(aL[1], aH[1], v.y);
        ACC_PAIR(aL[2], aH[2], v.z); ACC_PAIR(aL[3], aH[3], v.w);
    }

    float scA = inv[segA], scB = inv[segB];
    ushort8 rA, rB;
    #pragma unroll
    for (int t = 0; t < 4; ++t) {
        rA[2*t]   = f2b(aL[t] * scA);
        rA[2*t+1] = f2b(aH[t] * scA);
    }
    #pragma unroll
    for (int t = 0; t < 8; ++t) rB[t] = f2b(accB[t] * scB);
    *(ushort8*)(tbase)           = rA;
    *(ushort8*)(tbase + 4 * 512) = rB;
}

// ---------------- MFMA GEMM, LDS-free, swapped operands, FULL A-preload ----------------
// BM=64, 2 r16 tiles/wave. mfma(W_frag, A_frag): lane holds 4 consecutive FEATURES
// of one node -> float4/ushort4/uint vector stores, full 64B-line coverage.
__global__ __launch_bounds__(256) void gemm_mfma(
    const unsigned short* __restrict__ At, const unsigned short* __restrict__ x,
    const unsigned short* __restrict__ WTt, const float* __restrict__ bc,
    void* __restrict__ outp, unsigned char* __restrict__ out8,
    int relu, int write_f32, int N, int gd)
{
    const int tid = threadIdx.x;
    const int b   = blockIdx.x;
    const int isM = (b >= gd);
    const int row0   = isM ? N + (b - gd) * BM : b * BM;
    const int rowlim = isM ? 2 * N : N;
    const int tlim   = (rowlim >> 4) - 1;

    const float* bias = bc + isM * DD;

    const int wave = tid >> 6;
    const int lane = tid & 63;
    const int wc = (wave & 1) * 64;          // 0 / 64 (feature half)
    const int fr  = lane & 15;
    const int fk8 = lane >> 4;

    int r16a = (row0 >> 4) + (wave >> 1) * 2;
    int r16b = r16a + 1;
    if (r16a > tlim) r16a = tlim;
    if (r16b > tlim) r16b = tlim;

    const unsigned short* Abase0 = At + (size_t)r16a * 8 * 512 + lane * 8;
    const unsigned short* Abase1 = At + (size_t)r16b * 8 * 512 + lane * 8;
    const unsigned short* Xbase0 = x + (size_t)(r16a * 16 + fr) * DD + fk8 * 8;
    const unsigned short* Xbase1 = x + (size_t)(r16b * 16 + fr) * DD + fk8 * 8;
    const unsigned short* Wbase  = WTt + (size_t)isM * DD * KTOT + (size_t)(wc >> 4) * 12 * 512 + lane * 8;

    // ---- preload ALL A fragments: 24 independent loads issued back-to-back ----
    short8 aF0[12], aF1[12];
    #pragma unroll
    for (int k = 0; k < 8; ++k) {
        aF0[k] = *(const short8*)(Abase0 + k * 512);
        aF1[k] = *(const short8*)(Abase1 + k * 512);
    }
    #pragma unroll
    for (int k = 8; k < 12; ++k) {
        aF0[k] = *(const short8*)(Xbase0 + (k - 8) * 32);
        aF1[k] = *(const short8*)(Xbase1 + (k - 8) * 32);
    }

    floatx4 acc[2][4] = {};

    short8 bC[4], bN[4];
    #pragma unroll
    for (int c = 0; c < 4; ++c) bC[c] = *(const short8*)(Wbase + (size_t)c * 12 * 512);

    #pragma unroll
    for (int ks = 0; ks < 12; ++ks) {
        if (ks + 1 < 12) {
            #pragma unroll
            for (int c = 0; c < 4; ++c)
                bN[c] = *(const short8*)(Wbase + (size_t)c * 12 * 512 + (ks + 1) * 512);
        }
        // swapped operands: W as A-operand (rows=features), nodes as B-operand (cols)
        #pragma unroll
        for (int c = 0; c < 4; ++c) {
            acc[0][c] = __builtin_amdgcn_mfma_f32_16x16x32_bf16(bC[c], aF0[ks], acc[0][c], 0, 0, 0);
            acc[1][c] = __builtin_amdgcn_mfma_f32_16x16x32_bf16(bC[c], aF1[ks], acc[1][c], 0, 0, 0);
        }
        #pragma unroll
        for (int c = 0; c < 4; ++c) bC[c] = bN[c];
    }

    // epilogue: node = r16*16 + fr (col), feats = wc + c*16 + fk8*4 + i (rows) — vector stores
    float* outf = (float*)outp;
    unsigned short* outb = (unsigned short*)outp;
    const int rb = fk8 * 4;
    const int nodes[2] = { r16a * 16 + fr, r16b * 16 + fr };
    #pragma unroll
    for (int m = 0; m < 2; ++m) {
        size_t rowoff = (size_t)nodes[m] * DD;
        #pragma unroll
        for (int c = 0; c < 4; ++c) {
            int f0 = wc + c * 16 + rb;
            float4 bb = *(const float4*)(bias + f0);
            float v0 = acc[m][c][0] + bb.x;
            float v1 = acc[m][c][1] + bb.y;
            float v2 = acc[m][c][2] + bb.z;
            float v3 = acc[m][c][3] + bb.w;
            if (relu) {
                v0 = fmaxf(v0, 0.f); v1 = fmaxf(v1, 0.f);
                v2 = fmaxf(v2, 0.f); v3 = fmaxf(v3, 0.f);
            }
            if (write_f32) {
                *(float4*)(outf + rowoff + f0) = make_float4(v0, v1, v2, v3);
            } else {
                ushort4 h;
                h.x = f2b(v0); h.y = f2b(v1); h.z = f2b(v2); h.w = f2b(v3);
                *(ushort4*)(outb + rowoff + f0) = h;
                unsigned e = 0;
                e = __builtin_amdgcn_cvt_pk_fp8_f32(v0, v1, e, false);
                e = __builtin_amdgcn_cvt_pk_fp8_f32(v2, v3, e, true);
                *(unsigned*)(out8 + rowoff + f0) = e;
            }
        }
    }
}

extern "C" void kernel_launch(void* const* d_in, const int* in_sizes, int n_in,
                              void* d_out, int out_size, void* d_ws, size_t ws_size,
                              hipStream_t stream)
{
    const float* x_d = (const float*)d_in[0];
    const float* x_m = (const float*)d_in[1];
    const float* Wl  = (const float*)d_in[6];
    const float* bl  = (const float*)d_in[7];
    const float* Wr  = (const float*)d_in[8];
    float* out = (float*)d_out;

    const int N    = in_sizes[0] / DD;
    const int E_dd = in_sizes[2] / 2;
    const int E_mm = in_sizes[3] / 2;
    const int E_dm = in_sizes[4] / 2;
    const int E_md = in_sizes[5] / 2;
    const int E_tot = E_dd + E_md + E_mm + E_dm;
    const int n4 = 4 * N;
    const int nb = (n4 + BS - 1) >> BS_BITS;
    const int M16 = (2 * N + 15) >> 4;

    char* ws = (char*)d_ws;
    size_t off = 0;
    auto alloc = [&](size_t bytes) {
        void* p = ws + off;
        off += (bytes + 255) & ~(size_t)255;
        return p;
    };
    unsigned short* xb   = (unsigned short*)alloc((size_t)2 * N * DD * 2);  // [xd|xm] bf16
    unsigned short* hb   = (unsigned short*)alloc((size_t)2 * N * DD * 2);  // [hd|hm] bf16
    unsigned char*  x8   = (unsigned char*) alloc((size_t)2 * N * DD);      // fp8 mirror of x
    unsigned char*  h8   = (unsigned char*) alloc((size_t)2 * N * DD);      // fp8 mirror of h
    unsigned short* At   = (unsigned short*)alloc((size_t)M16 * 8 * 512 * 2);
    float* inv_all = (float*)alloc((size_t)n4 * 4);
    int*   rp_all  = (int*)  alloc((size_t)(n4 + 1) * 4);
    int*   bucket_fill = (int*)alloc((size_t)NBMAX * 4);   // adjacent with ovf_cnt: one memset
    int*   ovf_cnt = (int*)alloc(256);
    int*   bucket_base = (int*)alloc((size_t)NBMAX * 4);
    unsigned short* WTt = (unsigned short*)alloc((size_t)2 * 2 * DD * KTOT * 2);
    float* bc      = (float*)alloc((size_t)512 * 4);
    unsigned* stage = (unsigned*)alloc((size_t)nb * CAP * 4);
    int*   col     = (int*)alloc((size_t)E_tot * 4);
    unsigned long long* ovf = (unsigned long long*)alloc((size_t)(1 << 18) * 8);
    int*   flag    = (int*)alloc(256);

    // ---- edge dtype probe ----
    hipMemsetAsync(flag, 0, 256, stream);
    detect_i32<<<4, 256, 0, stream>>>((const int*)d_in[2], 1024, flag);

    // ---- x -> bf16 + fp8 mirror ([xd|xm] contiguous), single fused launch ----
    const int n8half = N * DD / 8;
    const int n8 = 2 * n8half;
    cvt_bf16<<<(n8 + 255) / 256, 256, 0, stream>>>(x_d, x_m, xb, x8, n8half, n8);

    // ---- CSR build: bin -> bucket scan -> per-bucket count/scan/fill ----
    hipMemsetAsync(bucket_fill, 0, (size_t)NBMAX * 4 + 256, stream);  // covers ovf_cnt too
    const int nchunks = (E_tot + CHUNK - 1) / CHUNK;
    bin_edges<<<nchunks, 512, 0, stream>>>(
        d_in[2], d_in[5], d_in[3], d_in[4], E_dd, E_md, E_mm, E_dm,
        flag, bucket_fill, stage, ovf, ovf_cnt, N, nb);
    scan_buckets<<<1, 512, 0, stream>>>(bucket_fill, nb, bucket_base);
    fill_from_stage<<<nb, 512, 0, stream>>>(
        stage, bucket_fill, bucket_base, ovf, ovf_cnt, rp_all, inv_all, col, n4);

    build_wcomb<<<(2 * 2 * DD * KTOT + 255) / 256, 256, 0, stream>>>(Wl, bl, Wr, WTt, bc);

    const int agg_grid = (int)(((size_t)2 * N * 16 + 255) / 256);
    const int gd = (N + BM - 1) / BM;
    const int gemm_grid = 2 * gd;
    const unsigned short* xcur = xb;
    const unsigned char*  xcur8 = x8;
    for (int l = 0; l < 2; ++l) {
        int relu = (l == 0);
        int wf32 = (l == 1);
        void* ob = (l == 1) ? (void*)out : (void*)hb;

        aggregate_all<<<agg_grid, 256, 0, stream>>>(xcur, xcur8, rp_all, inv_all, col, At, N);
        gemm_mfma<<<gemm_grid, 256, 0, stream>>>(
            At, xcur, WTt + (size_t)l * 2 * DD * KTOT, bc + l * 2 * DD,
            ob, h8, relu, wf32, N, gd);

        xcur = hb;
        xcur8 = h8;
    }
}